// Round 1
// baseline (612.732 us; speedup 1.0000x reference)
//
#include <hip/hip_runtime.h>
#include <math.h>

#define NEG_SLOPE 0.2f
#define LN_EPS 1e-5f

static __device__ __forceinline__ float lrelu(float e) {
    return e > 0.0f ? e : NEG_SLOPE * e;
}

// ---------------- zero int buffer ----------------
__global__ void k_zero(int* __restrict__ p, int n) {
    int i = blockIdx.x * blockDim.x + threadIdx.x;
    if (i < n) p[i] = 0;
}

// ---------------- GEMM1: h1 = x @ W1, + al_src1/al_dst1 ----------------
// x: [N,128], W1: [128,256], h1: [N,256]; block=256 threads, 16 rows/block
__global__ __launch_bounds__(256) void k_gemm1(
    const float* __restrict__ x, const float* __restrict__ W1,
    const float* __restrict__ as1, const float* __restrict__ ad1,
    float* __restrict__ h1, float* __restrict__ als, float* __restrict__ ald, int N)
{
    __shared__ float xs[16 * 128];
    const int tid = threadIdx.x;
    const int r0 = blockIdx.x * 16;

    // load 16 rows x 128 = 2048 floats = 512 float4
    float4* xs4 = (float4*)xs;
    const float4* xg = (const float4*)(x + (size_t)r0 * 128);
#pragma unroll
    for (int i = 0; i < 2; ++i) {
        int idx = tid + i * 256;             // 0..511
        int row = r0 + (idx >> 5);           // idx*4/128
        float4 v = make_float4(0.f, 0.f, 0.f, 0.f);
        if (row < N) v = xg[idx];
        xs4[idx] = v;
    }
    __syncthreads();

    const int col = tid;
    float acc[16];
#pragma unroll
    for (int r = 0; r < 16; ++r) acc[r] = 0.f;
    for (int k = 0; k < 128; ++k) {
        float w = W1[k * 256 + col];
#pragma unroll
        for (int r = 0; r < 16; ++r) acc[r] += xs[r * 128 + k] * w;
    }

    const int lane = tid & 63, wv = tid >> 6;   // wv == head
    const float a_s = as1[col], a_d = ad1[col];
#pragma unroll
    for (int r = 0; r < 16; ++r) {
        int row = r0 + r;
        if (row < N) h1[(size_t)row * 256 + col] = acc[r];
        float vs = acc[r] * a_s, vd = acc[r] * a_d;
#pragma unroll
        for (int o = 32; o; o >>= 1) { vs += __shfl_xor(vs, o); vd += __shfl_xor(vd, o); }
        if (lane == 0 && row < N) { als[row * 4 + wv] = vs; ald[row * 4 + wv] = vd; }
    }
}

// ---------------- degree histogram ----------------
__global__ void k_deg(const int* __restrict__ ei, int* __restrict__ deg, int E, int N) {
    int i = blockIdx.x * blockDim.x + threadIdx.x;
    int Et = E + N;
    if (i >= Et) return;
    int d = (i < E) ? ei[E + i] : (i - E);
    atomicAdd(&deg[d], 1);
}

// ---------------- single-block exclusive scan (N up to ~1M) ----------------
__global__ __launch_bounds__(1024) void k_scan(
    const int* __restrict__ deg, int* __restrict__ offs, int* __restrict__ cursor, int N)
{
    __shared__ int wsum[16];
    __shared__ int carry;
    const int tid = threadIdx.x, lane = tid & 63, wv = tid >> 6;
    if (tid == 0) carry = 0;
    __syncthreads();
    for (int base = 0; base < N; base += 1024) {
        int i = base + tid;
        int v = (i < N) ? deg[i] : 0;
        int xv = v;
#pragma unroll
        for (int o = 1; o < 64; o <<= 1) { int t = __shfl_up(xv, o); if (lane >= o) xv += t; }
        if (lane == 63) wsum[wv] = xv;
        __syncthreads();
        if (tid < 16) {
            int y = wsum[tid];
#pragma unroll
            for (int o = 1; o < 16; o <<= 1) { int t = __shfl_up(y, o); if (tid >= o) y += t; }
            wsum[tid] = y;
        }
        __syncthreads();
        int excl = (wv ? wsum[wv - 1] : 0) + carry + xv - v;
        if (i < N) { offs[i] = excl; cursor[i] = excl; }
        __syncthreads();
        if (tid == 0) carry += wsum[15];
        __syncthreads();
    }
    if (tid == 0) offs[N] = carry;
}

// ---------------- scatter src ids sorted by dst ----------------
__global__ void k_scatter(const int* __restrict__ ei, int* __restrict__ cursor,
                          int* __restrict__ eidx, int E, int N) {
    int i = blockIdx.x * blockDim.x + threadIdx.x;
    int Et = E + N;
    if (i >= Et) return;
    int s, d;
    if (i < E) { s = ei[i]; d = ei[E + i]; } else { s = d = i - E; }
    int pos = atomicAdd(&cursor[d], 1);
    eidx[pos] = s;
}

// ---------------- GAT layer-1 aggregation + bias + LN + ReLU ----------------
// one wave per node; lane owns features [4*lane, 4*lane+3]; head = lane>>4
__global__ __launch_bounds__(256) void k_agg1(
    const float* __restrict__ h1, const float* __restrict__ als, const float* __restrict__ ald,
    const int* __restrict__ offs, const int* __restrict__ eidx,
    const float* __restrict__ b1, const float* __restrict__ g1, const float* __restrict__ be1,
    float* __restrict__ hln1, int N)
{
    const int wv = threadIdx.x >> 6, lane = threadIdx.x & 63;
    int n = blockIdx.x * 4 + wv;
    if (n >= N) n = N - 1;   // duplicate work on tail; benign identical writes
    const int off0 = offs[n];
    const int deg = offs[n + 1] - off0;
    const float4 ad = ((const float4*)ald)[n];

    // pass 1: online softmax stats per head
    float m0 = -1e30f, m1 = -1e30f, m2 = -1e30f, m3 = -1e30f;
    float s0 = 0.f, s1 = 0.f, s2 = 0.f, s3 = 0.f;
    for (int j = lane; j < deg; j += 64) {
        int src = eidx[off0 + j];
        float4 a4 = ((const float4*)als)[src];
        float e, nm;
        e = lrelu(a4.x + ad.x); nm = fmaxf(m0, e); s0 = s0 * __expf(m0 - nm) + __expf(e - nm); m0 = nm;
        e = lrelu(a4.y + ad.y); nm = fmaxf(m1, e); s1 = s1 * __expf(m1 - nm) + __expf(e - nm); m1 = nm;
        e = lrelu(a4.z + ad.z); nm = fmaxf(m2, e); s2 = s2 * __expf(m2 - nm) + __expf(e - nm); m2 = nm;
        e = lrelu(a4.w + ad.w); nm = fmaxf(m3, e); s3 = s3 * __expf(m3 - nm) + __expf(e - nm); m3 = nm;
    }
#pragma unroll
    for (int o = 32; o; o >>= 1) {
        float mo, so, nm;
        mo = __shfl_xor(m0, o); so = __shfl_xor(s0, o);
        nm = fmaxf(m0, mo); s0 = s0 * __expf(m0 - nm) + so * __expf(mo - nm); m0 = nm;
        mo = __shfl_xor(m1, o); so = __shfl_xor(s1, o);
        nm = fmaxf(m1, mo); s1 = s1 * __expf(m1 - nm) + so * __expf(mo - nm); m1 = nm;
        mo = __shfl_xor(m2, o); so = __shfl_xor(s2, o);
        nm = fmaxf(m2, mo); s2 = s2 * __expf(m2 - nm) + so * __expf(mo - nm); m2 = nm;
        mo = __shfl_xor(m3, o); so = __shfl_xor(s3, o);
        nm = fmaxf(m3, mo); s3 = s3 * __expf(m3 - nm) + so * __expf(mo - nm); m3 = nm;
    }

    const int hd = lane >> 4;
    const float mh  = hd == 0 ? m0 : (hd == 1 ? m1 : (hd == 2 ? m2 : m3));
    const float sh_ = hd == 0 ? s0 : (hd == 1 ? s1 : (hd == 2 ? s2 : s3));
    const float adh = hd == 0 ? ad.x : (hd == 1 ? ad.y : (hd == 2 ? ad.z : ad.w));
    const float rd = 1.0f / sh_;

    float4 acc = make_float4(0.f, 0.f, 0.f, 0.f);
    for (int j = 0; j < deg; ++j) {
        int src = eidx[off0 + j];
        float alpha = __expf(lrelu(als[src * 4 + hd] + adh) - mh) * rd;
        float4 v = ((const float4*)(h1 + (size_t)src * 256))[lane];
        acc.x += alpha * v.x; acc.y += alpha * v.y;
        acc.z += alpha * v.z; acc.w += alpha * v.w;
    }

    // + b1, LayerNorm(256), ReLU
    float4 bb = ((const float4*)b1)[lane];
    float y0 = acc.x + bb.x, y1 = acc.y + bb.y, y2 = acc.z + bb.z, y3 = acc.w + bb.w;
    float ps = y0 + y1 + y2 + y3;
    float pss = y0 * y0 + y1 * y1 + y2 * y2 + y3 * y3;
#pragma unroll
    for (int o = 32; o; o >>= 1) { ps += __shfl_xor(ps, o); pss += __shfl_xor(pss, o); }
    float mu = ps * (1.f / 256.f);
    float var = pss * (1.f / 256.f) - mu * mu;
    float rstd = rsqrtf(var + LN_EPS);
    float4 gg = ((const float4*)g1)[lane];
    float4 b2v = ((const float4*)be1)[lane];
    float4 outv;
    outv.x = fmaxf((y0 - mu) * rstd * gg.x + b2v.x, 0.f);
    outv.y = fmaxf((y1 - mu) * rstd * gg.y + b2v.y, 0.f);
    outv.z = fmaxf((y2 - mu) * rstd * gg.z + b2v.z, 0.f);
    outv.w = fmaxf((y3 - mu) * rstd * gg.w + b2v.w, 0.f);
    ((float4*)(hln1 + (size_t)n * 256))[lane] = outv;
}

// ---------------- GEMM2: h2 = hln1 @ W2, + al_src2/al_dst2 ----------------
// hln1: [N,256], W2: [256,64]; block=256 threads, 16 rows/block
__global__ __launch_bounds__(256) void k_gemm2(
    const float* __restrict__ hln1, const float* __restrict__ W2,
    const float* __restrict__ as2, const float* __restrict__ ad2,
    float* __restrict__ h2, float* __restrict__ als2, float* __restrict__ ald2, int N)
{
    __shared__ float hs[16 * 256];
    const int tid = threadIdx.x;
    const int r0 = blockIdx.x * 16;
    float4* hs4 = (float4*)hs;
    const float4* hg = (const float4*)(hln1 + (size_t)r0 * 256);
#pragma unroll
    for (int i = 0; i < 4; ++i) {
        int idx = tid + i * 256;            // 0..1023
        int row = r0 + (idx >> 6);          // idx*4/256
        float4 v = make_float4(0.f, 0.f, 0.f, 0.f);
        if (row < N) v = hg[idx];
        hs4[idx] = v;
    }
    __syncthreads();

    const int col = tid & 63, sub = tid >> 6;   // sub == wave
    float acc[4] = {0.f, 0.f, 0.f, 0.f};
    for (int k = 0; k < 256; ++k) {
        float w = W2[k * 64 + col];
#pragma unroll
        for (int rr = 0; rr < 4; ++rr) acc[rr] += hs[(sub * 4 + rr) * 256 + k] * w;
    }
    const float a_s = as2[col], a_d = ad2[col];
#pragma unroll
    for (int rr = 0; rr < 4; ++rr) {
        int row = r0 + sub * 4 + rr;
        if (row < N) h2[(size_t)row * 64 + col] = acc[rr];
        float vs = acc[rr] * a_s, vd = acc[rr] * a_d;
#pragma unroll
        for (int o = 32; o; o >>= 1) { vs += __shfl_xor(vs, o); vd += __shfl_xor(vd, o); }
        if (col == 0 && row < N) { als2[row] = vs; ald2[row] = vd; }
    }
}

// ---------------- GAT layer-2 aggregation + bias + LN + ReLU + MLP head ----------------
__global__ __launch_bounds__(256) void k_agg2(
    const float* __restrict__ h2, const float* __restrict__ als, const float* __restrict__ ald,
    const int* __restrict__ offs, const int* __restrict__ eidx,
    const float* __restrict__ b2, const float* __restrict__ g2, const float* __restrict__ be2,
    const float* __restrict__ fc1W, const float* __restrict__ fc1b,
    const float* __restrict__ fc2W, const float* __restrict__ fc2b,
    float* __restrict__ out, int N)
{
    __shared__ float sh[4][64];
    const int wv = threadIdx.x >> 6, lane = threadIdx.x & 63;
    int n = blockIdx.x * 4 + wv;
    if (n >= N) n = N - 1;
    const int off0 = offs[n];
    const int deg = offs[n + 1] - off0;
    const float adn = ald[n];

    float m = -1e30f, s = 0.f;
    for (int j = lane; j < deg; j += 64) {
        int src = eidx[off0 + j];
        float e = lrelu(als[src] + adn);
        float nm = fmaxf(m, e);
        s = s * __expf(m - nm) + __expf(e - nm); m = nm;
    }
#pragma unroll
    for (int o = 32; o; o >>= 1) {
        float mo = __shfl_xor(m, o), so = __shfl_xor(s, o);
        float nm = fmaxf(m, mo);
        s = s * __expf(m - nm) + so * __expf(mo - nm); m = nm;
    }
    const float rd = 1.0f / s;

    float acc = 0.f;
    for (int j = 0; j < deg; ++j) {
        int src = eidx[off0 + j];
        float alpha = __expf(lrelu(als[src] + adn) - m) * rd;
        acc += alpha * h2[(size_t)src * 64 + lane];
    }

    float y = acc + b2[lane];
    float ps = y, pss = y * y;
#pragma unroll
    for (int o = 32; o; o >>= 1) { ps += __shfl_xor(ps, o); pss += __shfl_xor(pss, o); }
    float mu = ps * (1.f / 64.f);
    float var = pss * (1.f / 64.f) - mu * mu;
    float r = fmaxf((y - mu) * rsqrtf(var + LN_EPS) * g2[lane] + be2[lane], 0.f);

    sh[wv][lane] = r;
    __syncthreads();

    if (lane < 32) {
        float a1 = fc1b[lane];
#pragma unroll 8
        for (int k = 0; k < 64; ++k) a1 += sh[wv][k] * fc1W[k * 32 + lane];
        a1 = fmaxf(a1, 0.f);
        float t = a1 * fc2W[lane];
#pragma unroll
        for (int o = 16; o; o >>= 1) t += __shfl_xor(t, o);
        if (lane == 0) out[n] = t + fc2b[0];
    }
}

// ---------------- launch ----------------
extern "C" void kernel_launch(void* const* d_in, const int* in_sizes, int n_in,
                              void* d_out, int out_size, void* d_ws, size_t ws_size,
                              hipStream_t stream)
{
    const float* x   = (const float*)d_in[0];
    const int* ei    = (const int*)d_in[1];
    const float* W1  = (const float*)d_in[2];
    const float* as1 = (const float*)d_in[3];
    const float* ad1 = (const float*)d_in[4];
    const float* b1  = (const float*)d_in[5];
    const float* g1  = (const float*)d_in[6];
    const float* be1 = (const float*)d_in[7];
    const float* W2  = (const float*)d_in[8];
    const float* as2 = (const float*)d_in[9];
    const float* ad2 = (const float*)d_in[10];
    const float* b2  = (const float*)d_in[11];
    const float* g2  = (const float*)d_in[12];
    const float* be2 = (const float*)d_in[13];
    const float* fc1W = (const float*)d_in[14];
    const float* fc1b = (const float*)d_in[15];
    const float* fc2W = (const float*)d_in[16];
    const float* fc2b = (const float*)d_in[17];
    float* out = (float*)d_out;

    const int N = in_sizes[0] / 128;
    const int E = in_sizes[1] / 2;
    const int Et = E + N;

    // workspace carve (256B aligned)
    char* p = (char*)d_ws;
    auto carve = [&](size_t bytes) {
        void* q = p;
        p += (bytes + 255) & ~(size_t)255;
        return q;
    };
    float* h1   = (float*)carve((size_t)N * 256 * 4);
    float* hln1 = (float*)carve((size_t)N * 256 * 4);
    float* h2   = (float*)carve((size_t)N * 64 * 4);
    float* als1 = (float*)carve((size_t)N * 4 * 4);
    float* ald1 = (float*)carve((size_t)N * 4 * 4);
    float* als2 = (float*)carve((size_t)N * 4);
    float* ald2 = (float*)carve((size_t)N * 4);
    int* deg    = (int*)carve((size_t)N * 4);
    int* offs   = (int*)carve((size_t)(N + 1) * 4);
    int* cursor = (int*)carve((size_t)N * 4);
    int* eidx   = (int*)carve((size_t)Et * 4);

    // CSR build
    k_zero<<<(N + 255) / 256, 256, 0, stream>>>(deg, N);
    k_deg<<<(Et + 255) / 256, 256, 0, stream>>>(ei, deg, E, N);
    k_scan<<<1, 1024, 0, stream>>>(deg, offs, cursor, N);
    k_scatter<<<(Et + 255) / 256, 256, 0, stream>>>(ei, cursor, eidx, E, N);

    // layer 1
    k_gemm1<<<(N + 15) / 16, 256, 0, stream>>>(x, W1, as1, ad1, h1, als1, ald1, N);
    k_agg1<<<(N + 3) / 4, 256, 0, stream>>>(h1, als1, ald1, offs, eidx, b1, g1, be1, hln1, N);

    // layer 2
    k_gemm2<<<(N + 15) / 16, 256, 0, stream>>>(hln1, W2, as2, ad2, h2, als2, ald2, N);
    k_agg2<<<(N + 3) / 4, 256, 0, stream>>>(h2, als2, ald2, offs, eidx,
                                            b2, g2, be2, fc1W, fc1b, fc2W, fc2b, out, N);
}

// Round 2
// 539.901 us; speedup vs baseline: 1.1349x; 1.1349x over previous
//
#include <hip/hip_runtime.h>
#include <hip/hip_fp16.h>
#include <math.h>

#define NEG_SLOPE 0.2f
#define LN_EPS 1e-5f

typedef __attribute__((ext_vector_type(4))) _Float16 half4;

static __device__ __forceinline__ float lrelu(float e) {
    return e > 0.0f ? e : NEG_SLOPE * e;
}

// ---------------- zero int buffer ----------------
__global__ void k_zero(int* __restrict__ p, int n) {
    int i = blockIdx.x * blockDim.x + threadIdx.x;
    if (i < n) p[i] = 0;
}

// ---------------- GEMM1: h1 = x @ W1 (store fp16), + al_src1/al_dst1 (f32) ----------------
// x: [N,128], W1: [128,256]; block=256 threads, 16 rows/block
__global__ __launch_bounds__(256) void k_gemm1(
    const float* __restrict__ x, const float* __restrict__ W1,
    const float* __restrict__ as1, const float* __restrict__ ad1,
    _Float16* __restrict__ h1, float* __restrict__ als, float* __restrict__ ald, int N)
{
    __shared__ float xs[16 * 128];
    const int tid = threadIdx.x;
    const int r0 = blockIdx.x * 16;

    float4* xs4 = (float4*)xs;
    const float4* xg = (const float4*)(x + (size_t)r0 * 128);
#pragma unroll
    for (int i = 0; i < 2; ++i) {
        int idx = tid + i * 256;             // 0..511
        int row = r0 + (idx >> 5);
        float4 v = make_float4(0.f, 0.f, 0.f, 0.f);
        if (row < N) v = xg[idx];
        xs4[idx] = v;
    }
    __syncthreads();

    const int col = tid;
    float acc[16];
#pragma unroll
    for (int r = 0; r < 16; ++r) acc[r] = 0.f;

    for (int k4 = 0; k4 < 32; ++k4) {
        const float w0 = W1[(4 * k4 + 0) * 256 + col];
        const float w1 = W1[(4 * k4 + 1) * 256 + col];
        const float w2 = W1[(4 * k4 + 2) * 256 + col];
        const float w3 = W1[(4 * k4 + 3) * 256 + col];
#pragma unroll
        for (int r = 0; r < 16; ++r) {
            float4 xv = ((const float4*)(xs + r * 128))[k4];
            acc[r] = fmaf(xv.x, w0, acc[r]);
            acc[r] = fmaf(xv.y, w1, acc[r]);
            acc[r] = fmaf(xv.z, w2, acc[r]);
            acc[r] = fmaf(xv.w, w3, acc[r]);
        }
    }

    const int lane = tid & 63, wv = tid >> 6;   // wv == head
    const float a_s = as1[col], a_d = ad1[col];
#pragma unroll
    for (int r = 0; r < 16; ++r) {
        int row = r0 + r;
        if (row < N) h1[(size_t)row * 256 + col] = (_Float16)acc[r];
        float vs = acc[r] * a_s, vd = acc[r] * a_d;
#pragma unroll
        for (int o = 32; o; o >>= 1) { vs += __shfl_xor(vs, o); vd += __shfl_xor(vd, o); }
        if (lane == 0 && row < N) { als[row * 4 + wv] = vs; ald[row * 4 + wv] = vd; }
    }
}

// ---------------- degree histogram ----------------
__global__ void k_deg(const int* __restrict__ ei, int* __restrict__ deg, int E, int N) {
    int i = blockIdx.x * blockDim.x + threadIdx.x;
    int Et = E + N;
    if (i >= Et) return;
    int d = (i < E) ? ei[E + i] : (i - E);
    atomicAdd(&deg[d], 1);
}

// ---------------- single-block exclusive scan ----------------
__global__ __launch_bounds__(1024) void k_scan(
    const int* __restrict__ deg, int* __restrict__ offs, int* __restrict__ cursor, int N)
{
    __shared__ int wsum[16];
    __shared__ int carry;
    const int tid = threadIdx.x, lane = tid & 63, wv = tid >> 6;
    if (tid == 0) carry = 0;
    __syncthreads();
    for (int base = 0; base < N; base += 1024) {
        int i = base + tid;
        int v = (i < N) ? deg[i] : 0;
        int xv = v;
#pragma unroll
        for (int o = 1; o < 64; o <<= 1) { int t = __shfl_up(xv, o); if (lane >= o) xv += t; }
        if (lane == 63) wsum[wv] = xv;
        __syncthreads();
        if (tid < 16) {
            int y = wsum[tid];
#pragma unroll
            for (int o = 1; o < 16; o <<= 1) { int t = __shfl_up(y, o); if (tid >= o) y += t; }
            wsum[tid] = y;
        }
        __syncthreads();
        int excl = (wv ? wsum[wv - 1] : 0) + carry + xv - v;
        if (i < N) { offs[i] = excl; cursor[i] = excl; }
        __syncthreads();
        if (tid == 0) carry += wsum[15];
        __syncthreads();
    }
    if (tid == 0) offs[N] = carry;
}

// ---------------- scatter src ids sorted by dst ----------------
__global__ void k_scatter(const int* __restrict__ ei, int* __restrict__ cursor,
                          int* __restrict__ eidx, int E, int N) {
    int i = blockIdx.x * blockDim.x + threadIdx.x;
    int Et = E + N;
    if (i >= Et) return;
    int s, d;
    if (i < E) { s = ei[i]; d = ei[E + i]; } else { s = d = i - E; }
    int pos = atomicAdd(&cursor[d], 1);
    eidx[pos] = s;
}

// ---------------- GAT layer-1 aggregation + bias + LN + ReLU ----------------
// one wave per node; lane owns features [4*lane, 4*lane+3]; head = lane>>4
__global__ __launch_bounds__(256) void k_agg1(
    const _Float16* __restrict__ h1, const float* __restrict__ als, const float* __restrict__ ald,
    const int* __restrict__ offs, const int* __restrict__ eidx,
    const float* __restrict__ b1, const float* __restrict__ g1, const float* __restrict__ be1,
    float* __restrict__ hln1, int N)
{
    const int wv = threadIdx.x >> 6, lane = threadIdx.x & 63;
    int n = blockIdx.x * 4 + wv;
    if (n >= N) n = N - 1;   // tail duplicates work; identical writes, benign
    const int off0 = offs[n];
    const int deg = offs[n + 1] - off0;
    const float4 ad = ((const float4*)ald)[n];

    // pass 1: online softmax stats per head (edges striped over lanes)
    float m0 = -1e30f, m1 = -1e30f, m2 = -1e30f, m3 = -1e30f;
    float s0 = 0.f, s1 = 0.f, s2 = 0.f, s3 = 0.f;
    for (int j = lane; j < deg; j += 64) {
        int src = eidx[off0 + j];
        float4 a4 = ((const float4*)als)[src];
        float e, nm;
        e = lrelu(a4.x + ad.x); nm = fmaxf(m0, e); s0 = s0 * __expf(m0 - nm) + __expf(e - nm); m0 = nm;
        e = lrelu(a4.y + ad.y); nm = fmaxf(m1, e); s1 = s1 * __expf(m1 - nm) + __expf(e - nm); m1 = nm;
        e = lrelu(a4.z + ad.z); nm = fmaxf(m2, e); s2 = s2 * __expf(m2 - nm) + __expf(e - nm); m2 = nm;
        e = lrelu(a4.w + ad.w); nm = fmaxf(m3, e); s3 = s3 * __expf(m3 - nm) + __expf(e - nm); m3 = nm;
    }
#pragma unroll
    for (int o = 32; o; o >>= 1) {
        float mo, so, nm;
        mo = __shfl_xor(m0, o); so = __shfl_xor(s0, o);
        nm = fmaxf(m0, mo); s0 = s0 * __expf(m0 - nm) + so * __expf(mo - nm); m0 = nm;
        mo = __shfl_xor(m1, o); so = __shfl_xor(s1, o);
        nm = fmaxf(m1, mo); s1 = s1 * __expf(m1 - nm) + so * __expf(mo - nm); m1 = nm;
        mo = __shfl_xor(m2, o); so = __shfl_xor(s2, o);
        nm = fmaxf(m2, mo); s2 = s2 * __expf(m2 - nm) + so * __expf(mo - nm); m2 = nm;
        mo = __shfl_xor(m3, o); so = __shfl_xor(s3, o);
        nm = fmaxf(m3, mo); s3 = s3 * __expf(m3 - nm) + so * __expf(mo - nm); m3 = nm;
    }

    const int hd = lane >> 4;
    const float mh  = hd == 0 ? m0 : (hd == 1 ? m1 : (hd == 2 ? m2 : m3));
    const float sh_ = hd == 0 ? s0 : (hd == 1 ? s1 : (hd == 2 ? s2 : s3));
    const float adh = hd == 0 ? ad.x : (hd == 1 ? ad.y : (hd == 2 ? ad.z : ad.w));
    const float cc = -mh - __logf(sh_);       // alpha = exp(e + cc)

    // pass 2: sequential edges, lane owns 4 features (8B fp16 load), depth-1 prefetch
    float4 acc = make_float4(0.f, 0.f, 0.f, 0.f);
    int srcA = eidx[off0];
    for (int j = 0; j < deg; ++j) {
        int src = srcA;
        if (j + 1 < deg) srcA = eidx[off0 + j + 1];
        float alpha = __expf(lrelu(als[src * 4 + hd] + adh) + cc);
        half4 v = ((const half4*)(h1 + (size_t)src * 256))[lane];
        acc.x += alpha * (float)v.x; acc.y += alpha * (float)v.y;
        acc.z += alpha * (float)v.z; acc.w += alpha * (float)v.w;
    }

    // + b1, LayerNorm(256), ReLU
    float4 bb = ((const float4*)b1)[lane];
    float y0 = acc.x + bb.x, y1 = acc.y + bb.y, y2 = acc.z + bb.z, y3 = acc.w + bb.w;
    float ps = y0 + y1 + y2 + y3;
    float pss = y0 * y0 + y1 * y1 + y2 * y2 + y3 * y3;
#pragma unroll
    for (int o = 32; o; o >>= 1) { ps += __shfl_xor(ps, o); pss += __shfl_xor(pss, o); }
    float mu = ps * (1.f / 256.f);
    float var = pss * (1.f / 256.f) - mu * mu;
    float rstd = rsqrtf(var + LN_EPS);
    float4 gg = ((const float4*)g1)[lane];
    float4 b2v = ((const float4*)be1)[lane];
    float4 outv;
    outv.x = fmaxf((y0 - mu) * rstd * gg.x + b2v.x, 0.f);
    outv.y = fmaxf((y1 - mu) * rstd * gg.y + b2v.y, 0.f);
    outv.z = fmaxf((y2 - mu) * rstd * gg.z + b2v.z, 0.f);
    outv.w = fmaxf((y3 - mu) * rstd * gg.w + b2v.w, 0.f);
    ((float4*)(hln1 + (size_t)n * 256))[lane] = outv;
}

// ---------------- GEMM2: h2 = hln1 @ W2 (store fp16), + al_src2/al_dst2 ----------------
__global__ __launch_bounds__(256) void k_gemm2(
    const float* __restrict__ hln1, const float* __restrict__ W2,
    const float* __restrict__ as2, const float* __restrict__ ad2,
    _Float16* __restrict__ h2, float* __restrict__ als2, float* __restrict__ ald2, int N)
{
    __shared__ float hs[16 * 256];
    const int tid = threadIdx.x;
    const int r0 = blockIdx.x * 16;
    float4* hs4 = (float4*)hs;
    const float4* hg = (const float4*)(hln1 + (size_t)r0 * 256);
#pragma unroll
    for (int i = 0; i < 4; ++i) {
        int idx = tid + i * 256;            // 0..1023
        int row = r0 + (idx >> 6);
        float4 v = make_float4(0.f, 0.f, 0.f, 0.f);
        if (row < N) v = hg[idx];
        hs4[idx] = v;
    }
    __syncthreads();

    const int col = tid & 63, sub = tid >> 6;   // sub == wave
    float acc[4] = {0.f, 0.f, 0.f, 0.f};
    for (int k4 = 0; k4 < 64; ++k4) {
        const float w0 = W2[(4 * k4 + 0) * 64 + col];
        const float w1 = W2[(4 * k4 + 1) * 64 + col];
        const float w2 = W2[(4 * k4 + 2) * 64 + col];
        const float w3 = W2[(4 * k4 + 3) * 64 + col];
#pragma unroll
        for (int rr = 0; rr < 4; ++rr) {
            float4 hv = ((const float4*)(hs + (sub * 4 + rr) * 256))[k4];
            acc[rr] = fmaf(hv.x, w0, acc[rr]);
            acc[rr] = fmaf(hv.y, w1, acc[rr]);
            acc[rr] = fmaf(hv.z, w2, acc[rr]);
            acc[rr] = fmaf(hv.w, w3, acc[rr]);
        }
    }
    const float a_s = as2[col], a_d = ad2[col];
#pragma unroll
    for (int rr = 0; rr < 4; ++rr) {
        int row = r0 + sub * 4 + rr;
        if (row < N) h2[(size_t)row * 64 + col] = (_Float16)acc[rr];
        float vs = acc[rr] * a_s, vd = acc[rr] * a_d;
#pragma unroll
        for (int o = 32; o; o >>= 1) { vs += __shfl_xor(vs, o); vd += __shfl_xor(vd, o); }
        if (col == 0 && row < N) { als2[row] = vs; ald2[row] = vd; }
    }
}

// ---------------- GAT layer-2 aggregation + bias + LN + ReLU + MLP head ----------------
__global__ __launch_bounds__(256) void k_agg2(
    const _Float16* __restrict__ h2, const float* __restrict__ als, const float* __restrict__ ald,
    const int* __restrict__ offs, const int* __restrict__ eidx,
    const float* __restrict__ b2, const float* __restrict__ g2, const float* __restrict__ be2,
    const float* __restrict__ fc1W, const float* __restrict__ fc1b,
    const float* __restrict__ fc2W, const float* __restrict__ fc2b,
    float* __restrict__ out, int N)
{
    __shared__ float sh[4][64];
    const int wv = threadIdx.x >> 6, lane = threadIdx.x & 63;
    int n = blockIdx.x * 4 + wv;
    if (n >= N) n = N - 1;
    const int off0 = offs[n];
    const int deg = offs[n + 1] - off0;
    const float adn = ald[n];

    float m = -1e30f, s = 0.f;
    for (int j = lane; j < deg; j += 64) {
        int src = eidx[off0 + j];
        float e = lrelu(als[src] + adn);
        float nm = fmaxf(m, e);
        s = s * __expf(m - nm) + __expf(e - nm); m = nm;
    }
#pragma unroll
    for (int o = 32; o; o >>= 1) {
        float mo = __shfl_xor(m, o), so = __shfl_xor(s, o);
        float nm = fmaxf(m, mo);
        s = s * __expf(m - nm) + so * __expf(mo - nm); m = nm;
    }
    const float cc = -m - __logf(s);    // alpha = exp(e + cc)

    float acc = 0.f;
    int srcA = eidx[off0];
    for (int j = 0; j < deg; ++j) {
        int src = srcA;
        if (j + 1 < deg) srcA = eidx[off0 + j + 1];
        float alpha = __expf(lrelu(als[src] + adn) + cc);
        acc += alpha * (float)h2[(size_t)src * 64 + lane];
    }

    float y = acc + b2[lane];
    float ps = y, pss = y * y;
#pragma unroll
    for (int o = 32; o; o >>= 1) { ps += __shfl_xor(ps, o); pss += __shfl_xor(pss, o); }
    float mu = ps * (1.f / 64.f);
    float var = pss * (1.f / 64.f) - mu * mu;
    float r = fmaxf((y - mu) * rsqrtf(var + LN_EPS) * g2[lane] + be2[lane], 0.f);

    sh[wv][lane] = r;
    __syncthreads();

    if (lane < 32) {
        float a1 = fc1b[lane];
#pragma unroll 8
        for (int k = 0; k < 64; ++k) a1 += sh[wv][k] * fc1W[k * 32 + lane];
        a1 = fmaxf(a1, 0.f);
        float t = a1 * fc2W[lane];
#pragma unroll
        for (int o = 16; o; o >>= 1) t += __shfl_xor(t, o);
        if (lane == 0) out[n] = t + fc2b[0];
    }
}

// ---------------- launch ----------------
extern "C" void kernel_launch(void* const* d_in, const int* in_sizes, int n_in,
                              void* d_out, int out_size, void* d_ws, size_t ws_size,
                              hipStream_t stream)
{
    const float* x   = (const float*)d_in[0];
    const int* ei    = (const int*)d_in[1];
    const float* W1  = (const float*)d_in[2];
    const float* as1 = (const float*)d_in[3];
    const float* ad1 = (const float*)d_in[4];
    const float* b1  = (const float*)d_in[5];
    const float* g1  = (const float*)d_in[6];
    const float* be1 = (const float*)d_in[7];
    const float* W2  = (const float*)d_in[8];
    const float* as2 = (const float*)d_in[9];
    const float* ad2 = (const float*)d_in[10];
    const float* b2  = (const float*)d_in[11];
    const float* g2  = (const float*)d_in[12];
    const float* be2 = (const float*)d_in[13];
    const float* fc1W = (const float*)d_in[14];
    const float* fc1b = (const float*)d_in[15];
    const float* fc2W = (const float*)d_in[16];
    const float* fc2b = (const float*)d_in[17];
    float* out = (float*)d_out;

    const int N = in_sizes[0] / 128;
    const int E = in_sizes[1] / 2;
    const int Et = E + N;

    char* p = (char*)d_ws;
    auto carve = [&](size_t bytes) {
        void* q = p;
        p += (bytes + 255) & ~(size_t)255;
        return q;
    };
    _Float16* h1   = (_Float16*)carve((size_t)N * 256 * 2);
    float*    hln1 = (float*)carve((size_t)N * 256 * 4);
    _Float16* h2   = (_Float16*)carve((size_t)N * 64 * 2);
    float* als1 = (float*)carve((size_t)N * 4 * 4);
    float* ald1 = (float*)carve((size_t)N * 4 * 4);
    float* als2 = (float*)carve((size_t)N * 4);
    float* ald2 = (float*)carve((size_t)N * 4);
    int* deg    = (int*)carve((size_t)N * 4);
    int* offs   = (int*)carve((size_t)(N + 1) * 4);
    int* cursor = (int*)carve((size_t)N * 4);
    int* eidx   = (int*)carve((size_t)Et * 4);

    // CSR build
    k_zero<<<(N + 255) / 256, 256, 0, stream>>>(deg, N);
    k_deg<<<(Et + 255) / 256, 256, 0, stream>>>(ei, deg, E, N);
    k_scan<<<1, 1024, 0, stream>>>(deg, offs, cursor, N);
    k_scatter<<<(Et + 255) / 256, 256, 0, stream>>>(ei, cursor, eidx, E, N);

    // layer 1
    k_gemm1<<<(N + 15) / 16, 256, 0, stream>>>(x, W1, as1, ad1, h1, als1, ald1, N);
    k_agg1<<<(N + 3) / 4, 256, 0, stream>>>(h1, als1, ald1, offs, eidx, b1, g1, be1, hln1, N);

    // layer 2
    k_gemm2<<<(N + 15) / 16, 256, 0, stream>>>(hln1, W2, as2, ad2, h2, als2, ald2, N);
    k_agg2<<<(N + 3) / 4, 256, 0, stream>>>(h2, als2, ald2, offs, eidx,
                                            b2, g2, be2, fc1W, fc1b, fc2W, fc2b, out, N);
}

// Round 3
// 461.736 us; speedup vs baseline: 1.3270x; 1.1693x over previous
//
#include <hip/hip_runtime.h>
#include <hip/hip_fp16.h>
#include <math.h>

#define NEG_SLOPE 0.2f
#define LN_EPS 1e-5f

typedef __attribute__((ext_vector_type(8))) _Float16 half8;
typedef __attribute__((ext_vector_type(4))) _Float16 half4;
typedef __attribute__((ext_vector_type(4))) float floatx4;

static __device__ __forceinline__ float lrelu(float e) {
    return e > 0.0f ? e : NEG_SLOPE * e;
}

// ---------------- zero int buffer ----------------
__global__ void k_zero(int* __restrict__ p, int n) {
    int i = blockIdx.x * blockDim.x + threadIdx.x;
    if (i < n) p[i] = 0;
}

// ---------------- GEMM1 (MFMA fp16): h1 = x @ W1, + al_src1/al_dst1 ----------------
// x:[N,128] f32, W1:[128,256] f32. Block=4 waves; wave w owns cols [64w,64w+64) == head w.
// Each block: 32 rows (2 row-tiles of 16). B frags held in registers (W1 is L2-resident).
__global__ __launch_bounds__(256) void k_gemm1(
    const float* __restrict__ x, const float* __restrict__ W1,
    const float* __restrict__ as1, const float* __restrict__ ad1,
    _Float16* __restrict__ h1, float* __restrict__ als, float* __restrict__ ald, int N)
{
    const int lane = threadIdx.x & 63, w = threadIdx.x >> 6;
    const int l15 = lane & 15, quad = lane >> 4;
    const int r_base = blockIdx.x * 32;

    // B fragments: B[k][n], n = lane&15 (+16*nt+64*w), k = ks*32 + quad*8 + j
    half8 B[4][4];
    float asv[4], adv[4];
#pragma unroll
    for (int nt = 0; nt < 4; ++nt) {
        const int n = w * 64 + nt * 16 + l15;
        asv[nt] = as1[n]; adv[nt] = ad1[n];
#pragma unroll
        for (int ks = 0; ks < 4; ++ks) {
            const int k0 = ks * 32 + quad * 8;
            half8 b;
#pragma unroll
            for (int j = 0; j < 8; ++j) b[j] = (_Float16)W1[(size_t)(k0 + j) * 256 + n];
            B[ks][nt] = b;
        }
    }

#pragma unroll
    for (int rt = 0; rt < 2; ++rt) {
        const int r0 = r_base + rt * 16;
        int m = r0 + l15; if (m >= N) m = N - 1;
        half8 A[4];
#pragma unroll
        for (int ks = 0; ks < 4; ++ks) {
            const int k0 = ks * 32 + quad * 8;
            const float4* xp = (const float4*)(x + (size_t)m * 128 + k0);
            float4 v0 = xp[0], v1 = xp[1];
            half8 a;
            a[0] = (_Float16)v0.x; a[1] = (_Float16)v0.y; a[2] = (_Float16)v0.z; a[3] = (_Float16)v0.w;
            a[4] = (_Float16)v1.x; a[5] = (_Float16)v1.y; a[6] = (_Float16)v1.z; a[7] = (_Float16)v1.w;
            A[ks] = a;
        }
        floatx4 C[4];
#pragma unroll
        for (int nt = 0; nt < 4; ++nt) C[nt] = (floatx4){0.f, 0.f, 0.f, 0.f};
#pragma unroll
        for (int ks = 0; ks < 4; ++ks)
#pragma unroll
            for (int nt = 0; nt < 4; ++nt)
                C[nt] = __builtin_amdgcn_mfma_f32_16x16x32_f16(A[ks], B[ks][nt], C[nt], 0, 0, 0);

        // store h1 fp16 + fused attention-logit reduction (wave == head)
#pragma unroll
        for (int reg = 0; reg < 4; ++reg) {
            const int row = r0 + quad * 4 + reg;
            float vs = 0.f, vd = 0.f;
#pragma unroll
            for (int nt = 0; nt < 4; ++nt) {
                float c = C[nt][reg];
                if (row < N) h1[(size_t)row * 256 + w * 64 + nt * 16 + l15] = (_Float16)c;
                vs += c * asv[nt]; vd += c * adv[nt];
            }
#pragma unroll
            for (int o = 1; o < 16; o <<= 1) { vs += __shfl_xor(vs, o); vd += __shfl_xor(vd, o); }
            if (l15 == 0 && row < N) { als[row * 4 + w] = vs; ald[row * 4 + w] = vd; }
        }
    }
}

// ---------------- degree histogram ----------------
__global__ void k_deg(const int* __restrict__ ei, int* __restrict__ deg, int E, int N) {
    int i = blockIdx.x * blockDim.x + threadIdx.x;
    int Et = E + N;
    if (i >= Et) return;
    int d = (i < E) ? ei[E + i] : (i - E);
    atomicAdd(&deg[d], 1);
}

// ---------------- single-block exclusive scan ----------------
__global__ __launch_bounds__(1024) void k_scan(
    const int* __restrict__ deg, int* __restrict__ offs, int* __restrict__ cursor, int N)
{
    __shared__ int wsum[16];
    __shared__ int carry;
    const int tid = threadIdx.x, lane = tid & 63, wv = tid >> 6;
    if (tid == 0) carry = 0;
    __syncthreads();
    for (int base = 0; base < N; base += 1024) {
        int i = base + tid;
        int v = (i < N) ? deg[i] : 0;
        int xv = v;
#pragma unroll
        for (int o = 1; o < 64; o <<= 1) { int t = __shfl_up(xv, o); if (lane >= o) xv += t; }
        if (lane == 63) wsum[wv] = xv;
        __syncthreads();
        if (tid < 16) {
            int y = wsum[tid];
#pragma unroll
            for (int o = 1; o < 16; o <<= 1) { int t = __shfl_up(y, o); if (tid >= o) y += t; }
            wsum[tid] = y;
        }
        __syncthreads();
        int excl = (wv ? wsum[wv - 1] : 0) + carry + xv - v;
        if (i < N) { offs[i] = excl; cursor[i] = excl; }
        __syncthreads();
        if (tid == 0) carry += wsum[15];
        __syncthreads();
    }
    if (tid == 0) offs[N] = carry;
}

// ---------------- scatter src ids sorted by dst ----------------
__global__ void k_scatter(const int* __restrict__ ei, int* __restrict__ cursor,
                          int* __restrict__ eidx, int E, int N) {
    int i = blockIdx.x * blockDim.x + threadIdx.x;
    int Et = E + N;
    if (i >= Et) return;
    int s, d;
    if (i < E) { s = ei[i]; d = ei[E + i]; } else { s = d = i - E; }
    int pos = atomicAdd(&cursor[d], 1);
    eidx[pos] = s;
}

// ---------------- GAT layer-1 aggregation + bias + LN + ReLU (hln1 stored fp16) --------
// one wave per node; lane owns features [4*lane, 4*lane+3]; head = lane>>4
__global__ __launch_bounds__(256) void k_agg1(
    const _Float16* __restrict__ h1, const float* __restrict__ als, const float* __restrict__ ald,
    const int* __restrict__ offs, const int* __restrict__ eidx,
    const float* __restrict__ b1, const float* __restrict__ g1, const float* __restrict__ be1,
    _Float16* __restrict__ hln1, int N)
{
    const int wv = threadIdx.x >> 6, lane = threadIdx.x & 63;
    int n = blockIdx.x * 4 + wv;
    if (n >= N) n = N - 1;   // tail duplicates work; identical writes, benign
    const int off0 = offs[n];
    const int deg = offs[n + 1] - off0;
    const float4 ad = ((const float4*)ald)[n];

    // pass 1: online softmax stats per head (edges striped over lanes)
    float m0 = -1e30f, m1 = -1e30f, m2 = -1e30f, m3 = -1e30f;
    float s0 = 0.f, s1 = 0.f, s2 = 0.f, s3 = 0.f;
    for (int j = lane; j < deg; j += 64) {
        int src = eidx[off0 + j];
        float4 a4 = ((const float4*)als)[src];
        float e, nm;
        e = lrelu(a4.x + ad.x); nm = fmaxf(m0, e); s0 = s0 * __expf(m0 - nm) + __expf(e - nm); m0 = nm;
        e = lrelu(a4.y + ad.y); nm = fmaxf(m1, e); s1 = s1 * __expf(m1 - nm) + __expf(e - nm); m1 = nm;
        e = lrelu(a4.z + ad.z); nm = fmaxf(m2, e); s2 = s2 * __expf(m2 - nm) + __expf(e - nm); m2 = nm;
        e = lrelu(a4.w + ad.w); nm = fmaxf(m3, e); s3 = s3 * __expf(m3 - nm) + __expf(e - nm); m3 = nm;
    }
#pragma unroll
    for (int o = 32; o; o >>= 1) {
        float mo, so, nm;
        mo = __shfl_xor(m0, o); so = __shfl_xor(s0, o);
        nm = fmaxf(m0, mo); s0 = s0 * __expf(m0 - nm) + so * __expf(mo - nm); m0 = nm;
        mo = __shfl_xor(m1, o); so = __shfl_xor(s1, o);
        nm = fmaxf(m1, mo); s1 = s1 * __expf(m1 - nm) + so * __expf(mo - nm); m1 = nm;
        mo = __shfl_xor(m2, o); so = __shfl_xor(s2, o);
        nm = fmaxf(m2, mo); s2 = s2 * __expf(m2 - nm) + so * __expf(mo - nm); m2 = nm;
        mo = __shfl_xor(m3, o); so = __shfl_xor(s3, o);
        nm = fmaxf(m3, mo); s3 = s3 * __expf(m3 - nm) + so * __expf(mo - nm); m3 = nm;
    }

    const int hd = lane >> 4;
    const float mh  = hd == 0 ? m0 : (hd == 1 ? m1 : (hd == 2 ? m2 : m3));
    const float sh_ = hd == 0 ? s0 : (hd == 1 ? s1 : (hd == 2 ? s2 : s3));
    const float adh = hd == 0 ? ad.x : (hd == 1 ? ad.y : (hd == 2 ? ad.z : ad.w));
    const float cc = -mh - __logf(sh_);       // alpha = exp(e + cc)

    // pass 2: sequential edges, lane owns 4 features (8B fp16 load), depth-1 prefetch
    float4 acc = make_float4(0.f, 0.f, 0.f, 0.f);
    int srcA = eidx[off0];
    for (int j = 0; j < deg; ++j) {
        int src = srcA;
        if (j + 1 < deg) srcA = eidx[off0 + j + 1];
        float alpha = __expf(lrelu(als[src * 4 + hd] + adh) + cc);
        half4 v = ((const half4*)(h1 + (size_t)src * 256))[lane];
        acc.x += alpha * (float)v.x; acc.y += alpha * (float)v.y;
        acc.z += alpha * (float)v.z; acc.w += alpha * (float)v.w;
    }

    // + b1, LayerNorm(256), ReLU
    float4 bb = ((const float4*)b1)[lane];
    float y0 = acc.x + bb.x, y1 = acc.y + bb.y, y2 = acc.z + bb.z, y3 = acc.w + bb.w;
    float ps = y0 + y1 + y2 + y3;
    float pss = y0 * y0 + y1 * y1 + y2 * y2 + y3 * y3;
#pragma unroll
    for (int o = 32; o; o >>= 1) { ps += __shfl_xor(ps, o); pss += __shfl_xor(pss, o); }
    float mu = ps * (1.f / 256.f);
    float var = pss * (1.f / 256.f) - mu * mu;
    float rstd = rsqrtf(var + LN_EPS);
    float4 gg = ((const float4*)g1)[lane];
    float4 b2v = ((const float4*)be1)[lane];
    half4 outv;
    outv.x = (_Float16)fmaxf((y0 - mu) * rstd * gg.x + b2v.x, 0.f);
    outv.y = (_Float16)fmaxf((y1 - mu) * rstd * gg.y + b2v.y, 0.f);
    outv.z = (_Float16)fmaxf((y2 - mu) * rstd * gg.z + b2v.z, 0.f);
    outv.w = (_Float16)fmaxf((y3 - mu) * rstd * gg.w + b2v.w, 0.f);
    ((half4*)(hln1 + (size_t)n * 256))[lane] = outv;
}

// ---------------- GEMM2 (MFMA fp16): h2 = hln1 @ W2, + al_src2/al_dst2 ----------------
// hln1:[N,256] fp16, W2:[256,64] f32. Block=4 waves; wave w owns n-tile w (16 cols);
// block covers 64 rows x 64 cols. al reduction combined across waves via LDS.
__global__ __launch_bounds__(256) void k_gemm2(
    const _Float16* __restrict__ hln1, const float* __restrict__ W2,
    const float* __restrict__ as2, const float* __restrict__ ad2,
    _Float16* __restrict__ h2, float* __restrict__ als2, float* __restrict__ ald2, int N)
{
    __shared__ float ps_s[4][64], ps_d[4][64];
    const int lane = threadIdx.x & 63, w = threadIdx.x >> 6;
    const int l15 = lane & 15, quad = lane >> 4;
    const int r_base = blockIdx.x * 64;

    const int n = w * 16 + l15;
    const float asv = as2[n], adv = ad2[n];
    half8 B[8];
#pragma unroll
    for (int ks = 0; ks < 8; ++ks) {
        const int k0 = ks * 32 + quad * 8;
        half8 b;
#pragma unroll
        for (int j = 0; j < 8; ++j) b[j] = (_Float16)W2[(size_t)(k0 + j) * 64 + n];
        B[ks] = b;
    }

#pragma unroll
    for (int rt = 0; rt < 4; ++rt) {
        const int r0 = r_base + rt * 16;
        int m = r0 + l15; if (m >= N) m = N - 1;
        floatx4 C = (floatx4){0.f, 0.f, 0.f, 0.f};
#pragma unroll
        for (int ks = 0; ks < 8; ++ks) {
            half8 a = *(const half8*)(hln1 + (size_t)m * 256 + ks * 32 + quad * 8);
            C = __builtin_amdgcn_mfma_f32_16x16x32_f16(a, B[ks], C, 0, 0, 0);
        }
#pragma unroll
        for (int reg = 0; reg < 4; ++reg) {
            const int row = r0 + quad * 4 + reg;
            float c = C[reg];
            if (row < N) h2[(size_t)row * 64 + n] = (_Float16)c;
            float vs = c * asv, vd = c * adv;
#pragma unroll
            for (int o = 1; o < 16; o <<= 1) { vs += __shfl_xor(vs, o); vd += __shfl_xor(vd, o); }
            if (l15 == 0) {
                ps_s[w][rt * 16 + quad * 4 + reg] = vs;
                ps_d[w][rt * 16 + quad * 4 + reg] = vd;
            }
        }
    }
    __syncthreads();
    const int t = threadIdx.x;
    if (t < 64) {
        const int row = r_base + t;
        if (row < N) {
            als2[row] = ps_s[0][t] + ps_s[1][t] + ps_s[2][t] + ps_s[3][t];
            ald2[row] = ps_d[0][t] + ps_d[1][t] + ps_d[2][t] + ps_d[3][t];
        }
    }
}

// ---------------- GAT layer-2 aggregation + bias + LN + ReLU + MLP head ----------------
__global__ __launch_bounds__(256) void k_agg2(
    const _Float16* __restrict__ h2, const float* __restrict__ als, const float* __restrict__ ald,
    const int* __restrict__ offs, const int* __restrict__ eidx,
    const float* __restrict__ b2, const float* __restrict__ g2, const float* __restrict__ be2,
    const float* __restrict__ fc1W, const float* __restrict__ fc1b,
    const float* __restrict__ fc2W, const float* __restrict__ fc2b,
    float* __restrict__ out, int N)
{
    __shared__ float sh[4][64];
    const int wv = threadIdx.x >> 6, lane = threadIdx.x & 63;
    int n = blockIdx.x * 4 + wv;
    if (n >= N) n = N - 1;
    const int off0 = offs[n];
    const int deg = offs[n + 1] - off0;
    const float adn = ald[n];

    float m = -1e30f, s = 0.f;
    for (int j = lane; j < deg; j += 64) {
        int src = eidx[off0 + j];
        float e = lrelu(als[src] + adn);
        float nm = fmaxf(m, e);
        s = s * __expf(m - nm) + __expf(e - nm); m = nm;
    }
#pragma unroll
    for (int o = 32; o; o >>= 1) {
        float mo = __shfl_xor(m, o), so = __shfl_xor(s, o);
        float nm = fmaxf(m, mo);
        s = s * __expf(m - nm) + so * __expf(mo - nm); m = nm;
    }
    const float cc = -m - __logf(s);    // alpha = exp(e + cc)

    float acc = 0.f;
    int srcA = eidx[off0];
    for (int j = 0; j < deg; ++j) {
        int src = srcA;
        if (j + 1 < deg) srcA = eidx[off0 + j + 1];
        float alpha = __expf(lrelu(als[src] + adn) + cc);
        acc += alpha * (float)h2[(size_t)src * 64 + lane];
    }

    float y = acc + b2[lane];
    float ps = y, pss = y * y;
#pragma unroll
    for (int o = 32; o; o >>= 1) { ps += __shfl_xor(ps, o); pss += __shfl_xor(pss, o); }
    float mu = ps * (1.f / 64.f);
    float var = pss * (1.f / 64.f) - mu * mu;
    float r = fmaxf((y - mu) * rsqrtf(var + LN_EPS) * g2[lane] + be2[lane], 0.f);

    sh[wv][lane] = r;
    __syncthreads();

    if (lane < 32) {
        float a1 = fc1b[lane];
#pragma unroll 8
        for (int k = 0; k < 64; ++k) a1 += sh[wv][k] * fc1W[k * 32 + lane];
        a1 = fmaxf(a1, 0.f);
        float t = a1 * fc2W[lane];
#pragma unroll
        for (int o = 16; o; o >>= 1) t += __shfl_xor(t, o);
        if (lane == 0) out[n] = t + fc2b[0];
    }
}

// ---------------- launch ----------------
extern "C" void kernel_launch(void* const* d_in, const int* in_sizes, int n_in,
                              void* d_out, int out_size, void* d_ws, size_t ws_size,
                              hipStream_t stream)
{
    const float* x   = (const float*)d_in[0];
    const int* ei    = (const int*)d_in[1];
    const float* W1  = (const float*)d_in[2];
    const float* as1 = (const float*)d_in[3];
    const float* ad1 = (const float*)d_in[4];
    const float* b1  = (const float*)d_in[5];
    const float* g1  = (const float*)d_in[6];
    const float* be1 = (const float*)d_in[7];
    const float* W2  = (const float*)d_in[8];
    const float* as2 = (const float*)d_in[9];
    const float* ad2 = (const float*)d_in[10];
    const float* b2  = (const float*)d_in[11];
    const float* g2  = (const float*)d_in[12];
    const float* be2 = (const float*)d_in[13];
    const float* fc1W = (const float*)d_in[14];
    const float* fc1b = (const float*)d_in[15];
    const float* fc2W = (const float*)d_in[16];
    const float* fc2b = (const float*)d_in[17];
    float* out = (float*)d_out;

    const int N = in_sizes[0] / 128;
    const int E = in_sizes[1] / 2;
    const int Et = E + N;

    char* p = (char*)d_ws;
    auto carve = [&](size_t bytes) {
        void* q = p;
        p += (bytes + 255) & ~(size_t)255;
        return q;
    };
    _Float16* h1    = (_Float16*)carve((size_t)N * 256 * 2);
    _Float16* hln1h = (_Float16*)carve((size_t)N * 256 * 2);
    _Float16* h2    = (_Float16*)carve((size_t)N * 64 * 2);
    float* als1 = (float*)carve((size_t)N * 4 * 4);
    float* ald1 = (float*)carve((size_t)N * 4 * 4);
    float* als2 = (float*)carve((size_t)N * 4);
    float* ald2 = (float*)carve((size_t)N * 4);
    int* deg    = (int*)carve((size_t)N * 4);
    int* offs   = (int*)carve((size_t)(N + 1) * 4);
    int* cursor = (int*)carve((size_t)N * 4);
    int* eidx   = (int*)carve((size_t)Et * 4);

    // CSR build
    k_zero<<<(N + 255) / 256, 256, 0, stream>>>(deg, N);
    k_deg<<<(Et + 255) / 256, 256, 0, stream>>>(ei, deg, E, N);
    k_scan<<<1, 1024, 0, stream>>>(deg, offs, cursor, N);
    k_scatter<<<(Et + 255) / 256, 256, 0, stream>>>(ei, cursor, eidx, E, N);

    // layer 1
    k_gemm1<<<(N + 31) / 32, 256, 0, stream>>>(x, W1, as1, ad1, h1, als1, ald1, N);
    k_agg1<<<(N + 3) / 4, 256, 0, stream>>>(h1, als1, ald1, offs, eidx, b1, g1, be1, hln1h, N);

    // layer 2
    k_gemm2<<<(N + 63) / 64, 256, 0, stream>>>(hln1h, W2, as2, ad2, h2, als2, ald2, N);
    k_agg2<<<(N + 3) / 4, 256, 0, stream>>>(h2, als2, ald2, offs, eidx,
                                            b2, g2, be2, fc1W, fc1b, fc2W, fc2b, out, N);
}

// Round 4
// 414.642 us; speedup vs baseline: 1.4777x; 1.1136x over previous
//
#include <hip/hip_runtime.h>
#include <hip/hip_fp16.h>
#include <math.h>

#define NEG_SLOPE 0.2f
#define LN_EPS 1e-5f

typedef __attribute__((ext_vector_type(8))) _Float16 half8;
typedef __attribute__((ext_vector_type(4))) _Float16 half4;
typedef __attribute__((ext_vector_type(4))) float floatx4;

static __device__ __forceinline__ float lrelu(float e) {
    return e > 0.0f ? e : NEG_SLOPE * e;
}

// ---------------- zero int buffer ----------------
__global__ void k_zero(int* __restrict__ p, int n) {
    int i = blockIdx.x * blockDim.x + threadIdx.x;
    if (i < n) p[i] = 0;
}

// ---------------- GEMM1 (MFMA fp16): h1 = x @ W1, + al_src1/al_dst1 ----------------
// x:[N,128] f32, W1:[128,256] f32. Block=4 waves; wave w owns cols [64w,64w+64) == head w.
// Each block: 64 rows (4 row-tiles of 16). B frags held in registers (W1 is L2-resident).
__global__ __launch_bounds__(256) void k_gemm1(
    const float* __restrict__ x, const float* __restrict__ W1,
    const float* __restrict__ as1, const float* __restrict__ ad1,
    _Float16* __restrict__ h1, float* __restrict__ als, float* __restrict__ ald, int N)
{
    const int lane = threadIdx.x & 63, w = threadIdx.x >> 6;
    const int l15 = lane & 15, quad = lane >> 4;
    const int r_base = blockIdx.x * 64;

    // B fragments: B[k][n], n = lane&15 (+16*nt+64*w), k = ks*32 + quad*8 + j
    half8 B[4][4];
    float asv[4], adv[4];
#pragma unroll
    for (int nt = 0; nt < 4; ++nt) {
        const int n = w * 64 + nt * 16 + l15;
        asv[nt] = as1[n]; adv[nt] = ad1[n];
#pragma unroll
        for (int ks = 0; ks < 4; ++ks) {
            const int k0 = ks * 32 + quad * 8;
            half8 b;
#pragma unroll
            for (int j = 0; j < 8; ++j) b[j] = (_Float16)W1[(size_t)(k0 + j) * 256 + n];
            B[ks][nt] = b;
        }
    }

#pragma unroll
    for (int rt = 0; rt < 4; ++rt) {
        const int r0 = r_base + rt * 16;
        int m = r0 + l15; if (m >= N) m = N - 1;
        half8 A[4];
#pragma unroll
        for (int ks = 0; ks < 4; ++ks) {
            const int k0 = ks * 32 + quad * 8;
            const float4* xp = (const float4*)(x + (size_t)m * 128 + k0);
            float4 v0 = xp[0], v1 = xp[1];
            half8 a;
            a[0] = (_Float16)v0.x; a[1] = (_Float16)v0.y; a[2] = (_Float16)v0.z; a[3] = (_Float16)v0.w;
            a[4] = (_Float16)v1.x; a[5] = (_Float16)v1.y; a[6] = (_Float16)v1.z; a[7] = (_Float16)v1.w;
            A[ks] = a;
        }
        floatx4 C[4];
#pragma unroll
        for (int nt = 0; nt < 4; ++nt) C[nt] = (floatx4){0.f, 0.f, 0.f, 0.f};
#pragma unroll
        for (int ks = 0; ks < 4; ++ks)
#pragma unroll
            for (int nt = 0; nt < 4; ++nt)
                C[nt] = __builtin_amdgcn_mfma_f32_16x16x32_f16(A[ks], B[ks][nt], C[nt], 0, 0, 0);

        // store h1 fp16 + fused attention-logit reduction (wave == head)
#pragma unroll
        for (int reg = 0; reg < 4; ++reg) {
            const int row = r0 + quad * 4 + reg;
            float vs = 0.f, vd = 0.f;
#pragma unroll
            for (int nt = 0; nt < 4; ++nt) {
                float c = C[nt][reg];
                if (row < N) h1[(size_t)row * 256 + w * 64 + nt * 16 + l15] = (_Float16)c;
                vs += c * asv[nt]; vd += c * adv[nt];
            }
#pragma unroll
            for (int o = 1; o < 16; o <<= 1) { vs += __shfl_xor(vs, o); vd += __shfl_xor(vd, o); }
            if (l15 == 0 && row < N) { als[row * 4 + w] = vs; ald[row * 4 + w] = vd; }
        }
    }
}

// ---------------- degree histogram ----------------
__global__ void k_deg(const int* __restrict__ ei, int* __restrict__ deg, int E, int N) {
    int i = blockIdx.x * blockDim.x + threadIdx.x;
    int Et = E + N;
    if (i >= Et) return;
    int d = (i < E) ? ei[E + i] : (i - E);
    atomicAdd(&deg[d], 1);
}

// ---------------- single-block exclusive scan ----------------
__global__ __launch_bounds__(1024) void k_scan(
    const int* __restrict__ deg, int* __restrict__ offs, int* __restrict__ cursor, int N)
{
    __shared__ int wsum[16];
    __shared__ int carry;
    const int tid = threadIdx.x, lane = tid & 63, wv = tid >> 6;
    if (tid == 0) carry = 0;
    __syncthreads();
    for (int base = 0; base < N; base += 1024) {
        int i = base + tid;
        int v = (i < N) ? deg[i] : 0;
        int xv = v;
#pragma unroll
        for (int o = 1; o < 64; o <<= 1) { int t = __shfl_up(xv, o); if (lane >= o) xv += t; }
        if (lane == 63) wsum[wv] = xv;
        __syncthreads();
        if (tid < 16) {
            int y = wsum[tid];
#pragma unroll
            for (int o = 1; o < 16; o <<= 1) { int t = __shfl_up(y, o); if (tid >= o) y += t; }
            wsum[tid] = y;
        }
        __syncthreads();
        int excl = (wv ? wsum[wv - 1] : 0) + carry + xv - v;
        if (i < N) { offs[i] = excl; cursor[i] = excl; }
        __syncthreads();
        if (tid == 0) carry += wsum[15];
        __syncthreads();
    }
    if (tid == 0) offs[N] = carry;
}

// ---------------- scatter src ids sorted by dst ----------------
__global__ void k_scatter(const int* __restrict__ ei, int* __restrict__ cursor,
                          int* __restrict__ eidx, int E, int N) {
    int i = blockIdx.x * blockDim.x + threadIdx.x;
    int Et = E + N;
    if (i >= Et) return;
    int s, d;
    if (i < E) { s = ei[i]; d = ei[E + i]; } else { s = d = i - E; }
    int pos = atomicAdd(&cursor[d], 1);
    eidx[pos] = s;
}

// ---------------- GAT layer-1 aggregation + bias + LN + ReLU (hln1 stored fp16) --------
// one wave per node; lane owns features [4*lane, 4*lane+3]; head = lane>>4.
// pass 2: 16-edge chunks; lane (hd,l15) computes alpha(edge l15, head hd) once;
// inner loop: src via v_readlane (SGPR saddr), alpha via ds_bpermute, 4 loads in flight.
__global__ __launch_bounds__(256) void k_agg1(
    const _Float16* __restrict__ h1, const float* __restrict__ als, const float* __restrict__ ald,
    const int* __restrict__ offs, const int* __restrict__ eidx,
    const float* __restrict__ b1, const float* __restrict__ g1, const float* __restrict__ be1,
    _Float16* __restrict__ hln1, int N)
{
    const int wv = threadIdx.x >> 6, lane = threadIdx.x & 63;
    int n = blockIdx.x * 4 + wv;
    if (n >= N) n = N - 1;   // tail duplicates work; identical writes, benign
    const int off0 = offs[n];
    const int deg = offs[n + 1] - off0;
    const float4 ad = ((const float4*)ald)[n];

    // pass 1: online softmax stats per head (edges striped over lanes)
    float m0 = -1e30f, m1 = -1e30f, m2 = -1e30f, m3 = -1e30f;
    float s0 = 0.f, s1 = 0.f, s2 = 0.f, s3 = 0.f;
    for (int j = lane; j < deg; j += 64) {
        int src = eidx[off0 + j];
        float4 a4 = ((const float4*)als)[src];
        float e, nm;
        e = lrelu(a4.x + ad.x); nm = fmaxf(m0, e); s0 = s0 * __expf(m0 - nm) + __expf(e - nm); m0 = nm;
        e = lrelu(a4.y + ad.y); nm = fmaxf(m1, e); s1 = s1 * __expf(m1 - nm) + __expf(e - nm); m1 = nm;
        e = lrelu(a4.z + ad.z); nm = fmaxf(m2, e); s2 = s2 * __expf(m2 - nm) + __expf(e - nm); m2 = nm;
        e = lrelu(a4.w + ad.w); nm = fmaxf(m3, e); s3 = s3 * __expf(m3 - nm) + __expf(e - nm); m3 = nm;
    }
#pragma unroll
    for (int o = 32; o; o >>= 1) {
        float mo, so, nm;
        mo = __shfl_xor(m0, o); so = __shfl_xor(s0, o);
        nm = fmaxf(m0, mo); s0 = s0 * __expf(m0 - nm) + so * __expf(mo - nm); m0 = nm;
        mo = __shfl_xor(m1, o); so = __shfl_xor(s1, o);
        nm = fmaxf(m1, mo); s1 = s1 * __expf(m1 - nm) + so * __expf(mo - nm); m1 = nm;
        mo = __shfl_xor(m2, o); so = __shfl_xor(s2, o);
        nm = fmaxf(m2, mo); s2 = s2 * __expf(m2 - nm) + so * __expf(mo - nm); m2 = nm;
        mo = __shfl_xor(m3, o); so = __shfl_xor(s3, o);
        nm = fmaxf(m3, mo); s3 = s3 * __expf(m3 - nm) + so * __expf(mo - nm); m3 = nm;
    }

    const int hd = lane >> 4, l15 = lane & 15;
    const float mh  = hd == 0 ? m0 : (hd == 1 ? m1 : (hd == 2 ? m2 : m3));
    const float sh_ = hd == 0 ? s0 : (hd == 1 ? s1 : (hd == 2 ? s2 : s3));
    const float adh = hd == 0 ? ad.x : (hd == 1 ? ad.y : (hd == 2 ? ad.z : ad.w));
    const float cc = -mh - __logf(sh_);       // alpha = exp(e + cc)

    // pass 2: chunks of 16 edges
    float4 acc = make_float4(0.f, 0.f, 0.f, 0.f);
    const int bp_base = (lane & 48) << 2;     // (hd*16)*4 byte addr for bpermute
    for (int c0 = 0; c0 < deg; c0 += 16) {
        int nc = deg - c0; if (nc > 16) nc = 16;
        int j = c0 + l15; if (j >= deg) j = deg - 1;   // clamp => safe src
        int srcv = eidx[off0 + j];
        float alpha = __expf(lrelu(als[srcv * 4 + hd] + adh) + cc);
        if (l15 >= nc) alpha = 0.f;                    // masked edges contribute 0
        for (int e0 = 0; e0 < nc; e0 += 4) {
            // up to 4 independent row loads in flight; e0 <= 12 so e <= 15 always
#pragma unroll
            for (int u = 0; u < 4; ++u) {
                const int e = e0 + u;
                int s = __builtin_amdgcn_readlane(srcv, e);
                float a_e = __int_as_float(
                    __builtin_amdgcn_ds_bpermute(bp_base + e * 4, __float_as_int(alpha)));
                half4 v = *(const half4*)(h1 + (size_t)s * 256 + 4 * lane);
                acc.x = fmaf((float)v.x, a_e, acc.x);
                acc.y = fmaf((float)v.y, a_e, acc.y);
                acc.z = fmaf((float)v.z, a_e, acc.z);
                acc.w = fmaf((float)v.w, a_e, acc.w);
            }
        }
    }

    // + b1, LayerNorm(256), ReLU
    float4 bb = ((const float4*)b1)[lane];
    float y0 = acc.x + bb.x, y1 = acc.y + bb.y, y2 = acc.z + bb.z, y3 = acc.w + bb.w;
    float ps = y0 + y1 + y2 + y3;
    float pss = y0 * y0 + y1 * y1 + y2 * y2 + y3 * y3;
#pragma unroll
    for (int o = 32; o; o >>= 1) { ps += __shfl_xor(ps, o); pss += __shfl_xor(pss, o); }
    float mu = ps * (1.f / 256.f);
    float var = pss * (1.f / 256.f) - mu * mu;
    float rstd = rsqrtf(var + LN_EPS);
    float4 gg = ((const float4*)g1)[lane];
    float4 b2v = ((const float4*)be1)[lane];
    half4 outv;
    outv.x = (_Float16)fmaxf((y0 - mu) * rstd * gg.x + b2v.x, 0.f);
    outv.y = (_Float16)fmaxf((y1 - mu) * rstd * gg.y + b2v.y, 0.f);
    outv.z = (_Float16)fmaxf((y2 - mu) * rstd * gg.z + b2v.z, 0.f);
    outv.w = (_Float16)fmaxf((y3 - mu) * rstd * gg.w + b2v.w, 0.f);
    ((half4*)(hln1 + (size_t)n * 256))[lane] = outv;
}

// ---------------- GEMM2 (MFMA fp16): h2 = hln1 @ W2, + al_src2/al_dst2 ----------------
__global__ __launch_bounds__(256) void k_gemm2(
    const _Float16* __restrict__ hln1, const float* __restrict__ W2,
    const float* __restrict__ as2, const float* __restrict__ ad2,
    _Float16* __restrict__ h2, float* __restrict__ als2, float* __restrict__ ald2, int N)
{
    __shared__ float ps_s[4][64], ps_d[4][64];
    const int lane = threadIdx.x & 63, w = threadIdx.x >> 6;
    const int l15 = lane & 15, quad = lane >> 4;
    const int r_base = blockIdx.x * 64;

    const int n = w * 16 + l15;
    const float asv = as2[n], adv = ad2[n];
    half8 B[8];
#pragma unroll
    for (int ks = 0; ks < 8; ++ks) {
        const int k0 = ks * 32 + quad * 8;
        half8 b;
#pragma unroll
        for (int j = 0; j < 8; ++j) b[j] = (_Float16)W2[(size_t)(k0 + j) * 64 + n];
        B[ks] = b;
    }

#pragma unroll
    for (int rt = 0; rt < 4; ++rt) {
        const int r0 = r_base + rt * 16;
        int m = r0 + l15; if (m >= N) m = N - 1;
        floatx4 C = (floatx4){0.f, 0.f, 0.f, 0.f};
#pragma unroll
        for (int ks = 0; ks < 8; ++ks) {
            half8 a = *(const half8*)(hln1 + (size_t)m * 256 + ks * 32 + quad * 8);
            C = __builtin_amdgcn_mfma_f32_16x16x32_f16(a, B[ks], C, 0, 0, 0);
        }
#pragma unroll
        for (int reg = 0; reg < 4; ++reg) {
            const int row = r0 + quad * 4 + reg;
            float c = C[reg];
            if (row < N) h2[(size_t)row * 64 + n] = (_Float16)c;
            float vs = c * asv, vd = c * adv;
#pragma unroll
            for (int o = 1; o < 16; o <<= 1) { vs += __shfl_xor(vs, o); vd += __shfl_xor(vd, o); }
            if (l15 == 0) {
                ps_s[w][rt * 16 + quad * 4 + reg] = vs;
                ps_d[w][rt * 16 + quad * 4 + reg] = vd;
            }
        }
    }
    __syncthreads();
    const int t = threadIdx.x;
    if (t < 64) {
        const int row = r_base + t;
        if (row < N) {
            als2[row] = ps_s[0][t] + ps_s[1][t] + ps_s[2][t] + ps_s[3][t];
            ald2[row] = ps_d[0][t] + ps_d[1][t] + ps_d[2][t] + ps_d[3][t];
        }
    }
}

// ---------------- GAT layer-2 aggregation + bias + LN + ReLU + MLP head ----------------
// pass 2: 64-edge chunks; lane computes alpha for edge c0+lane; src+alpha via readlane.
__global__ __launch_bounds__(256) void k_agg2(
    const _Float16* __restrict__ h2, const float* __restrict__ als, const float* __restrict__ ald,
    const int* __restrict__ offs, const int* __restrict__ eidx,
    const float* __restrict__ b2, const float* __restrict__ g2, const float* __restrict__ be2,
    const float* __restrict__ fc1W, const float* __restrict__ fc1b,
    const float* __restrict__ fc2W, const float* __restrict__ fc2b,
    float* __restrict__ out, int N)
{
    __shared__ float sh[4][64];
    const int wv = threadIdx.x >> 6, lane = threadIdx.x & 63;
    int n = blockIdx.x * 4 + wv;
    if (n >= N) n = N - 1;
    const int off0 = offs[n];
    const int deg = offs[n + 1] - off0;
    const float adn = ald[n];

    float m = -1e30f, s = 0.f;
    for (int j = lane; j < deg; j += 64) {
        int src = eidx[off0 + j];
        float e = lrelu(als[src] + adn);
        float nm = fmaxf(m, e);
        s = s * __expf(m - nm) + __expf(e - nm); m = nm;
    }
#pragma unroll
    for (int o = 32; o; o >>= 1) {
        float mo = __shfl_xor(m, o), so = __shfl_xor(s, o);
        float nm = fmaxf(m, mo);
        s = s * __expf(m - nm) + so * __expf(mo - nm); m = nm;
    }
    const float cc = -m - __logf(s);    // alpha = exp(e + cc)

    float acc = 0.f;
    for (int c0 = 0; c0 < deg; c0 += 64) {
        int nc = deg - c0; if (nc > 64) nc = 64;
        int j = c0 + lane; if (j >= deg) j = deg - 1;   // clamp => safe src
        int srcv = eidx[off0 + j];
        float alpha = __expf(lrelu(als[srcv] + adn) + cc);
        if (lane >= nc) alpha = 0.f;
        for (int e0 = 0; e0 < nc; e0 += 4) {
#pragma unroll
            for (int u = 0; u < 4; ++u) {
                const int e = e0 + u;                  // e0 <= 60, e <= 63 always
                int sidx = __builtin_amdgcn_readlane(srcv, e);
                float a_e = __int_as_float(
                    __builtin_amdgcn_readlane(__float_as_int(alpha), e));
                acc = fmaf((float)h2[(size_t)sidx * 64 + lane], a_e, acc);
            }
        }
    }

    float y = acc + b2[lane];
    float ps = y, pss = y * y;
#pragma unroll
    for (int o = 32; o; o >>= 1) { ps += __shfl_xor(ps, o); pss += __shfl_xor(pss, o); }
    float mu = ps * (1.f / 64.f);
    float var = pss * (1.f / 64.f) - mu * mu;
    float r = fmaxf((y - mu) * rsqrtf(var + LN_EPS) * g2[lane] + be2[lane], 0.f);

    sh[wv][lane] = r;
    __syncthreads();

    if (lane < 32) {
        float a1 = fc1b[lane];
#pragma unroll 8
        for (int k = 0; k < 64; ++k) a1 += sh[wv][k] * fc1W[k * 32 + lane];
        a1 = fmaxf(a1, 0.f);
        float t = a1 * fc2W[lane];
#pragma unroll
        for (int o = 16; o; o >>= 1) t += __shfl_xor(t, o);
        if (lane == 0) out[n] = t + fc2b[0];
    }
}

// ---------------- launch ----------------
extern "C" void kernel_launch(void* const* d_in, const int* in_sizes, int n_in,
                              void* d_out, int out_size, void* d_ws, size_t ws_size,
                              hipStream_t stream)
{
    const float* x   = (const float*)d_in[0];
    const int* ei    = (const int*)d_in[1];
    const float* W1  = (const float*)d_in[2];
    const float* as1 = (const float*)d_in[3];
    const float* ad1 = (const float*)d_in[4];
    const float* b1  = (const float*)d_in[5];
    const float* g1  = (const float*)d_in[6];
    const float* be1 = (const float*)d_in[7];
    const float* W2  = (const float*)d_in[8];
    const float* as2 = (const float*)d_in[9];
    const float* ad2 = (const float*)d_in[10];
    const float* b2  = (const float*)d_in[11];
    const float* g2  = (const float*)d_in[12];
    const float* be2 = (const float*)d_in[13];
    const float* fc1W = (const float*)d_in[14];
    const float* fc1b = (const float*)d_in[15];
    const float* fc2W = (const float*)d_in[16];
    const float* fc2b = (const float*)d_in[17];
    float* out = (float*)d_out;

    const int N = in_sizes[0] / 128;
    const int E = in_sizes[1] / 2;
    const int Et = E + N;

    char* p = (char*)d_ws;
    auto carve = [&](size_t bytes) {
        void* q = p;
        p += (bytes + 255) & ~(size_t)255;
        return q;
    };
    _Float16* h1    = (_Float16*)carve((size_t)N * 256 * 2);
    _Float16* hln1h = (_Float16*)carve((size_t)N * 256 * 2);
    _Float16* h2    = (_Float16*)carve((size_t)N * 64 * 2);
    float* als1 = (float*)carve((size_t)N * 4 * 4);
    float* ald1 = (float*)carve((size_t)N * 4 * 4);
    float* als2 = (float*)carve((size_t)N * 4);
    float* ald2 = (float*)carve((size_t)N * 4);
    int* deg    = (int*)carve((size_t)N * 4);
    int* offs   = (int*)carve((size_t)(N + 1) * 4);
    int* cursor = (int*)carve((size_t)N * 4);
    int* eidx   = (int*)carve((size_t)Et * 4);

    // CSR build
    k_zero<<<(N + 255) / 256, 256, 0, stream>>>(deg, N);
    k_deg<<<(Et + 255) / 256, 256, 0, stream>>>(ei, deg, E, N);
    k_scan<<<1, 1024, 0, stream>>>(deg, offs, cursor, N);
    k_scatter<<<(Et + 255) / 256, 256, 0, stream>>>(ei, cursor, eidx, E, N);

    // layer 1
    k_gemm1<<<(N + 63) / 64, 256, 0, stream>>>(x, W1, as1, ad1, h1, als1, ald1, N);
    k_agg1<<<(N + 3) / 4, 256, 0, stream>>>(h1, als1, ald1, offs, eidx, b1, g1, be1, hln1h, N);

    // layer 2
    k_gemm2<<<(N + 63) / 64, 256, 0, stream>>>(hln1h, W2, as2, ad2, h2, als2, ald2, N);
    k_agg2<<<(N + 3) / 4, 256, 0, stream>>>(h2, als2, ald2, offs, eidx,
                                            b2, g2, be2, fc1W, fc1b, fc2W, fc2b, out, N);
}

// Round 5
// 313.769 us; speedup vs baseline: 1.9528x; 1.3215x over previous
//
#include <hip/hip_runtime.h>
#include <hip/hip_fp16.h>
#include <math.h>

#define NEG_SLOPE 0.2f
#define LN_EPS 1e-5f

typedef __attribute__((ext_vector_type(8))) _Float16 half8;
typedef __attribute__((ext_vector_type(4))) _Float16 half4;
typedef __attribute__((ext_vector_type(4))) float floatx4;

static __device__ __forceinline__ float lrelu(float e) {
    return e > 0.0f ? e : NEG_SLOPE * e;
}

// ---------------- zero int buffer ----------------
__global__ void k_zero(int* __restrict__ p, int n) {
    int i = blockIdx.x * blockDim.x + threadIdx.x;
    if (i < n) p[i] = 0;
}

// ================= CSR build: two-level LDS-staged counting sort ==============
// Buckets of 128 nodes (dst>>7). Edge i in [0,E) = (ei[i], ei[E+i]); i in [E,Et) = self-loop.

// per-block LDS bucket histogram -> global bucket counts (few atomics)
__global__ __launch_bounds__(256) void k_bcount(
    const int* __restrict__ ei, int* __restrict__ gcount, int E, int N, int NB)
{
    __shared__ int hist[512];
    const int Et = E + N;
    for (int t = threadIdx.x; t < NB; t += 256) hist[t] = 0;
    __syncthreads();
    const int i0 = blockIdx.x * 8192;
#pragma unroll 4
    for (int j = 0; j < 32; ++j) {
        int i = i0 + j * 256 + threadIdx.x;
        if (i < Et) {
            int d = (i < E) ? ei[E + i] : (i - E);
            atomicAdd(&hist[d >> 7], 1);
        }
    }
    __syncthreads();
    for (int t = threadIdx.x; t < NB; t += 256)
        if (hist[t]) atomicAdd(&gcount[t], hist[t]);
}

// parallel exclusive scan of NB (<512) bucket counts; init cursor; offs[N]=Et
__global__ __launch_bounds__(512) void k_bscan(
    const int* __restrict__ gcount, int* __restrict__ gbase, int* __restrict__ gcursor,
    int* __restrict__ offs, int NB, int N, int Et)
{
    __shared__ int ws[8];
    const int t = threadIdx.x, lane = t & 63, w = t >> 6;
    int v = (t < NB) ? gcount[t] : 0;
    int x = v;
#pragma unroll
    for (int o = 1; o < 64; o <<= 1) { int u = __shfl_up(x, o); if (lane >= o) x += u; }
    if (lane == 63) ws[w] = x;
    __syncthreads();
    if (t < 8) {
        int y = ws[t];
#pragma unroll
        for (int o = 1; o < 8; o <<= 1) { int u = __shfl_up(y, o); if (t >= o) y += u; }
        ws[t] = y;
    }
    __syncthreads();
    int excl = x - v + (w ? ws[w - 1] : 0);
    if (t < NB) { gbase[t] = excl; gcursor[t] = excl; }
    if (t == 0) offs[N] = Et;
}

// stage (src,dst) pairs grouped by bucket: LDS hist -> per-(block,bucket) reservation -> write
__global__ __launch_bounds__(256) void k_bscatter(
    const int* __restrict__ ei, int* __restrict__ gcursor, int2* __restrict__ staged,
    int E, int N, int NB)
{
    __shared__ int hist[512];
    __shared__ int lbase[512];
    const int Et = E + N;
    for (int t = threadIdx.x; t < NB; t += 256) hist[t] = 0;
    __syncthreads();
    const int i0 = blockIdx.x * 8192;
#pragma unroll 4
    for (int j = 0; j < 32; ++j) {
        int i = i0 + j * 256 + threadIdx.x;
        if (i < Et) {
            int d = (i < E) ? ei[E + i] : (i - E);
            atomicAdd(&hist[d >> 7], 1);
        }
    }
    __syncthreads();
    for (int t = threadIdx.x; t < NB; t += 256) {
        int c = hist[t];
        lbase[t] = c ? atomicAdd(&gcursor[t], c) : 0;
    }
    __syncthreads();
    for (int t = threadIdx.x; t < NB; t += 256) hist[t] = 0;
    __syncthreads();
#pragma unroll 4
    for (int j = 0; j < 32; ++j) {
        int i = i0 + j * 256 + threadIdx.x;
        if (i < Et) {
            int s, d;
            if (i < E) { s = ei[i]; d = ei[E + i]; } else { s = d = i - E; }
            int b = d >> 7;
            int k = atomicAdd(&hist[b], 1);
            staged[lbase[b] + k] = make_int2(s, d);
        }
    }
}

// one block per bucket: node histogram + scan -> offs; LDS-cursor scatter -> eidx
__global__ __launch_bounds__(256) void k_bbuild(
    const int2* __restrict__ staged, const int* __restrict__ gcount, const int* __restrict__ gbase,
    int* __restrict__ offs, int* __restrict__ eidx, int N)
{
    __shared__ int ncnt[128];
    __shared__ int lcur[128];
    const int b = blockIdx.x;
    const int node0 = b << 7;
    const int base = gbase[b], cnt = gcount[b];
    for (int t = threadIdx.x; t < 128; t += 256) ncnt[t] = 0;
    __syncthreads();
    for (int t = threadIdx.x; t < cnt; t += 256)
        atomicAdd(&ncnt[staged[base + t].y - node0], 1);
    __syncthreads();
    if (threadIdx.x < 64) {
        const int lane = threadIdx.x;
        int a0 = ncnt[lane], a1 = ncnt[64 + lane];
        int x0 = a0, x1 = a1;
#pragma unroll
        for (int o = 1; o < 64; o <<= 1) {
            int t0 = __shfl_up(x0, o), t1 = __shfl_up(x1, o);
            if (lane >= o) { x0 += t0; x1 += t1; }
        }
        int tot0 = __shfl(x0, 63);
        int e0 = base + x0 - a0;
        int e1 = base + x1 - a1 + tot0;
        lcur[lane] = e0; lcur[64 + lane] = e1;
        int na = node0 + lane, nb = node0 + 64 + lane;
        if (na < N) offs[na] = e0;
        if (nb < N) offs[nb] = e1;
    }
    __syncthreads();
    for (int t = threadIdx.x; t < cnt; t += 256) {
        int2 sd = staged[base + t];
        int pos = atomicAdd(&lcur[sd.y - node0], 1);
        eidx[pos] = sd.x;
    }
}

// ---------------- GEMM1 (MFMA fp16): h1 = x @ W1, + al_src1/al_dst1 ----------------
__global__ __launch_bounds__(256) void k_gemm1(
    const float* __restrict__ x, const float* __restrict__ W1,
    const float* __restrict__ as1, const float* __restrict__ ad1,
    _Float16* __restrict__ h1, float* __restrict__ als, float* __restrict__ ald, int N)
{
    const int lane = threadIdx.x & 63, w = threadIdx.x >> 6;
    const int l15 = lane & 15, quad = lane >> 4;
    const int r_base = blockIdx.x * 64;

    half8 B[4][4];
    float asv[4], adv[4];
#pragma unroll
    for (int nt = 0; nt < 4; ++nt) {
        const int n = w * 64 + nt * 16 + l15;
        asv[nt] = as1[n]; adv[nt] = ad1[n];
#pragma unroll
        for (int ks = 0; ks < 4; ++ks) {
            const int k0 = ks * 32 + quad * 8;
            half8 b;
#pragma unroll
            for (int j = 0; j < 8; ++j) b[j] = (_Float16)W1[(size_t)(k0 + j) * 256 + n];
            B[ks][nt] = b;
        }
    }

#pragma unroll
    for (int rt = 0; rt < 4; ++rt) {
        const int r0 = r_base + rt * 16;
        int m = r0 + l15; if (m >= N) m = N - 1;
        half8 A[4];
#pragma unroll
        for (int ks = 0; ks < 4; ++ks) {
            const int k0 = ks * 32 + quad * 8;
            const float4* xp = (const float4*)(x + (size_t)m * 128 + k0);
            float4 v0 = xp[0], v1 = xp[1];
            half8 a;
            a[0] = (_Float16)v0.x; a[1] = (_Float16)v0.y; a[2] = (_Float16)v0.z; a[3] = (_Float16)v0.w;
            a[4] = (_Float16)v1.x; a[5] = (_Float16)v1.y; a[6] = (_Float16)v1.z; a[7] = (_Float16)v1.w;
            A[ks] = a;
        }
        floatx4 C[4];
#pragma unroll
        for (int nt = 0; nt < 4; ++nt) C[nt] = (floatx4){0.f, 0.f, 0.f, 0.f};
#pragma unroll
        for (int ks = 0; ks < 4; ++ks)
#pragma unroll
            for (int nt = 0; nt < 4; ++nt)
                C[nt] = __builtin_amdgcn_mfma_f32_16x16x32_f16(A[ks], B[ks][nt], C[nt], 0, 0, 0);

#pragma unroll
        for (int reg = 0; reg < 4; ++reg) {
            const int row = r0 + quad * 4 + reg;
            float vs = 0.f, vd = 0.f;
#pragma unroll
            for (int nt = 0; nt < 4; ++nt) {
                float c = C[nt][reg];
                if (row < N) h1[(size_t)row * 256 + w * 64 + nt * 16 + l15] = (_Float16)c;
                vs += c * asv[nt]; vd += c * adv[nt];
            }
#pragma unroll
            for (int o = 1; o < 16; o <<= 1) { vs += __shfl_xor(vs, o); vd += __shfl_xor(vd, o); }
            if (l15 == 0 && row < N) { als[row * 4 + w] = vs; ald[row * 4 + w] = vd; }
        }
    }
}

// ---------------- GAT layer-1 aggregation + bias + LN + ReLU (hln1 stored fp16) --------
__global__ __launch_bounds__(256) void k_agg1(
    const _Float16* __restrict__ h1, const float* __restrict__ als, const float* __restrict__ ald,
    const int* __restrict__ offs, const int* __restrict__ eidx,
    const float* __restrict__ b1, const float* __restrict__ g1, const float* __restrict__ be1,
    _Float16* __restrict__ hln1, int N)
{
    const int wv = threadIdx.x >> 6, lane = threadIdx.x & 63;
    int n = blockIdx.x * 4 + wv;
    if (n >= N) n = N - 1;   // tail duplicates work; identical writes, benign
    const int off0 = offs[n];
    const int deg = offs[n + 1] - off0;
    const float4 ad = ((const float4*)ald)[n];

    float m0 = -1e30f, m1 = -1e30f, m2 = -1e30f, m3 = -1e30f;
    float s0 = 0.f, s1 = 0.f, s2 = 0.f, s3 = 0.f;
    for (int j = lane; j < deg; j += 64) {
        int src = eidx[off0 + j];
        float4 a4 = ((const float4*)als)[src];
        float e, nm;
        e = lrelu(a4.x + ad.x); nm = fmaxf(m0, e); s0 = s0 * __expf(m0 - nm) + __expf(e - nm); m0 = nm;
        e = lrelu(a4.y + ad.y); nm = fmaxf(m1, e); s1 = s1 * __expf(m1 - nm) + __expf(e - nm); m1 = nm;
        e = lrelu(a4.z + ad.z); nm = fmaxf(m2, e); s2 = s2 * __expf(m2 - nm) + __expf(e - nm); m2 = nm;
        e = lrelu(a4.w + ad.w); nm = fmaxf(m3, e); s3 = s3 * __expf(m3 - nm) + __expf(e - nm); m3 = nm;
    }
#pragma unroll
    for (int o = 32; o; o >>= 1) {
        float mo, so, nm;
        mo = __shfl_xor(m0, o); so = __shfl_xor(s0, o);
        nm = fmaxf(m0, mo); s0 = s0 * __expf(m0 - nm) + so * __expf(mo - nm); m0 = nm;
        mo = __shfl_xor(m1, o); so = __shfl_xor(s1, o);
        nm = fmaxf(m1, mo); s1 = s1 * __expf(m1 - nm) + so * __expf(mo - nm); m1 = nm;
        mo = __shfl_xor(m2, o); so = __shfl_xor(s2, o);
        nm = fmaxf(m2, mo); s2 = s2 * __expf(m2 - nm) + so * __expf(mo - nm); m2 = nm;
        mo = __shfl_xor(m3, o); so = __shfl_xor(s3, o);
        nm = fmaxf(m3, mo); s3 = s3 * __expf(m3 - nm) + so * __expf(mo - nm); m3 = nm;
    }

    const int hd = lane >> 4, l15 = lane & 15;
    const float mh  = hd == 0 ? m0 : (hd == 1 ? m1 : (hd == 2 ? m2 : m3));
    const float sh_ = hd == 0 ? s0 : (hd == 1 ? s1 : (hd == 2 ? s2 : s3));
    const float adh = hd == 0 ? ad.x : (hd == 1 ? ad.y : (hd == 2 ? ad.z : ad.w));
    const float cc = -mh - __logf(sh_);       // alpha = exp(e + cc)

    float4 acc = make_float4(0.f, 0.f, 0.f, 0.f);
    const int bp_base = (lane & 48) << 2;     // (hd*16)*4 byte addr for bpermute
    for (int c0 = 0; c0 < deg; c0 += 16) {
        int nc = deg - c0; if (nc > 16) nc = 16;
        int j = c0 + l15; if (j >= deg) j = deg - 1;   // clamp => safe src
        int srcv = eidx[off0 + j];
        float alpha = __expf(lrelu(als[srcv * 4 + hd] + adh) + cc);
        if (l15 >= nc) alpha = 0.f;                    // masked edges contribute 0
        for (int e0 = 0; e0 < nc; e0 += 4) {
#pragma unroll
            for (int u = 0; u < 4; ++u) {
                const int e = e0 + u;
                int s = __builtin_amdgcn_readlane(srcv, e);
                float a_e = __int_as_float(
                    __builtin_amdgcn_ds_bpermute(bp_base + e * 4, __float_as_int(alpha)));
                half4 v = *(const half4*)(h1 + (size_t)s * 256 + 4 * lane);
                acc.x = fmaf((float)v.x, a_e, acc.x);
                acc.y = fmaf((float)v.y, a_e, acc.y);
                acc.z = fmaf((float)v.z, a_e, acc.z);
                acc.w = fmaf((float)v.w, a_e, acc.w);
            }
        }
    }

    float4 bb = ((const float4*)b1)[lane];
    float y0 = acc.x + bb.x, y1 = acc.y + bb.y, y2 = acc.z + bb.z, y3 = acc.w + bb.w;
    float ps = y0 + y1 + y2 + y3;
    float pss = y0 * y0 + y1 * y1 + y2 * y2 + y3 * y3;
#pragma unroll
    for (int o = 32; o; o >>= 1) { ps += __shfl_xor(ps, o); pss += __shfl_xor(pss, o); }
    float mu = ps * (1.f / 256.f);
    float var = pss * (1.f / 256.f) - mu * mu;
    float rstd = rsqrtf(var + LN_EPS);
    float4 gg = ((const float4*)g1)[lane];
    float4 b2v = ((const float4*)be1)[lane];
    half4 outv;
    outv.x = (_Float16)fmaxf((y0 - mu) * rstd * gg.x + b2v.x, 0.f);
    outv.y = (_Float16)fmaxf((y1 - mu) * rstd * gg.y + b2v.y, 0.f);
    outv.z = (_Float16)fmaxf((y2 - mu) * rstd * gg.z + b2v.z, 0.f);
    outv.w = (_Float16)fmaxf((y3 - mu) * rstd * gg.w + b2v.w, 0.f);
    ((half4*)(hln1 + (size_t)n * 256))[lane] = outv;
}

// ---------------- GEMM2 (MFMA fp16): h2 = hln1 @ W2, + al_src2/al_dst2 ----------------
__global__ __launch_bounds__(256) void k_gemm2(
    const _Float16* __restrict__ hln1, const float* __restrict__ W2,
    const float* __restrict__ as2, const float* __restrict__ ad2,
    _Float16* __restrict__ h2, float* __restrict__ als2, float* __restrict__ ald2, int N)
{
    __shared__ float ps_s[4][64], ps_d[4][64];
    const int lane = threadIdx.x & 63, w = threadIdx.x >> 6;
    const int l15 = lane & 15, quad = lane >> 4;
    const int r_base = blockIdx.x * 64;

    const int n = w * 16 + l15;
    const float asv = as2[n], adv = ad2[n];
    half8 B[8];
#pragma unroll
    for (int ks = 0; ks < 8; ++ks) {
        const int k0 = ks * 32 + quad * 8;
        half8 b;
#pragma unroll
        for (int j = 0; j < 8; ++j) b[j] = (_Float16)W2[(size_t)(k0 + j) * 64 + n];
        B[ks] = b;
    }

#pragma unroll
    for (int rt = 0; rt < 4; ++rt) {
        const int r0 = r_base + rt * 16;
        int m = r0 + l15; if (m >= N) m = N - 1;
        floatx4 C = (floatx4){0.f, 0.f, 0.f, 0.f};
#pragma unroll
        for (int ks = 0; ks < 8; ++ks) {
            half8 a = *(const half8*)(hln1 + (size_t)m * 256 + ks * 32 + quad * 8);
            C = __builtin_amdgcn_mfma_f32_16x16x32_f16(a, B[ks], C, 0, 0, 0);
        }
#pragma unroll
        for (int reg = 0; reg < 4; ++reg) {
            const int row = r0 + quad * 4 + reg;
            float c = C[reg];
            if (row < N) h2[(size_t)row * 64 + n] = (_Float16)c;
            float vs = c * asv, vd = c * adv;
#pragma unroll
            for (int o = 1; o < 16; o <<= 1) { vs += __shfl_xor(vs, o); vd += __shfl_xor(vd, o); }
            if (l15 == 0) {
                ps_s[w][rt * 16 + quad * 4 + reg] = vs;
                ps_d[w][rt * 16 + quad * 4 + reg] = vd;
            }
        }
    }
    __syncthreads();
    const int t = threadIdx.x;
    if (t < 64) {
        const int row = r_base + t;
        if (row < N) {
            als2[row] = ps_s[0][t] + ps_s[1][t] + ps_s[2][t] + ps_s[3][t];
            ald2[row] = ps_d[0][t] + ps_d[1][t] + ps_d[2][t] + ps_d[3][t];
        }
    }
}

// ---------------- GAT layer-2 aggregation + bias + LN + ReLU + MLP head ----------------
__global__ __launch_bounds__(256) void k_agg2(
    const _Float16* __restrict__ h2, const float* __restrict__ als, const float* __restrict__ ald,
    const int* __restrict__ offs, const int* __restrict__ eidx,
    const float* __restrict__ b2, const float* __restrict__ g2, const float* __restrict__ be2,
    const float* __restrict__ fc1W, const float* __restrict__ fc1b,
    const float* __restrict__ fc2W, const float* __restrict__ fc2b,
    float* __restrict__ out, int N)
{
    __shared__ float sh[4][64];
    const int wv = threadIdx.x >> 6, lane = threadIdx.x & 63;
    int n = blockIdx.x * 4 + wv;
    if (n >= N) n = N - 1;
    const int off0 = offs[n];
    const int deg = offs[n + 1] - off0;
    const float adn = ald[n];

    float m = -1e30f, s = 0.f;
    for (int j = lane; j < deg; j += 64) {
        int src = eidx[off0 + j];
        float e = lrelu(als[src] + adn);
        float nm = fmaxf(m, e);
        s = s * __expf(m - nm) + __expf(e - nm); m = nm;
    }
#pragma unroll
    for (int o = 32; o; o >>= 1) {
        float mo = __shfl_xor(m, o), so = __shfl_xor(s, o);
        float nm = fmaxf(m, mo);
        s = s * __expf(m - nm) + so * __expf(mo - nm); m = nm;
    }
    const float cc = -m - __logf(s);    // alpha = exp(e + cc)

    float acc = 0.f;
    for (int c0 = 0; c0 < deg; c0 += 64) {
        int nc = deg - c0; if (nc > 64) nc = 64;
        int j = c0 + lane; if (j >= deg) j = deg - 1;   // clamp => safe src
        int srcv = eidx[off0 + j];
        float alpha = __expf(lrelu(als[srcv] + adn) + cc);
        if (lane >= nc) alpha = 0.f;
        for (int e0 = 0; e0 < nc; e0 += 4) {
#pragma unroll
            for (int u = 0; u < 4; ++u) {
                const int e = e0 + u;                  // e0 <= 60, e <= 63 always
                int sidx = __builtin_amdgcn_readlane(srcv, e);
                float a_e = __int_as_float(
                    __builtin_amdgcn_readlane(__float_as_int(alpha), e));
                acc = fmaf((float)h2[(size_t)sidx * 64 + lane], a_e, acc);
            }
        }
    }

    float y = acc + b2[lane];
    float ps = y, pss = y * y;
#pragma unroll
    for (int o = 32; o; o >>= 1) { ps += __shfl_xor(ps, o); pss += __shfl_xor(pss, o); }
    float mu = ps * (1.f / 64.f);
    float var = pss * (1.f / 64.f) - mu * mu;
    float r = fmaxf((y - mu) * rsqrtf(var + LN_EPS) * g2[lane] + be2[lane], 0.f);

    sh[wv][lane] = r;
    __syncthreads();

    if (lane < 32) {
        float a1 = fc1b[lane];
#pragma unroll 8
        for (int k = 0; k < 64; ++k) a1 += sh[wv][k] * fc1W[k * 32 + lane];
        a1 = fmaxf(a1, 0.f);
        float t = a1 * fc2W[lane];
#pragma unroll
        for (int o = 16; o; o >>= 1) t += __shfl_xor(t, o);
        if (lane == 0) out[n] = t + fc2b[0];
    }
}

// ---------------- launch ----------------
extern "C" void kernel_launch(void* const* d_in, const int* in_sizes, int n_in,
                              void* d_out, int out_size, void* d_ws, size_t ws_size,
                              hipStream_t stream)
{
    const float* x   = (const float*)d_in[0];
    const int* ei    = (const int*)d_in[1];
    const float* W1  = (const float*)d_in[2];
    const float* as1 = (const float*)d_in[3];
    const float* ad1 = (const float*)d_in[4];
    const float* b1  = (const float*)d_in[5];
    const float* g1  = (const float*)d_in[6];
    const float* be1 = (const float*)d_in[7];
    const float* W2  = (const float*)d_in[8];
    const float* as2 = (const float*)d_in[9];
    const float* ad2 = (const float*)d_in[10];
    const float* b2  = (const float*)d_in[11];
    const float* g2  = (const float*)d_in[12];
    const float* be2 = (const float*)d_in[13];
    const float* fc1W = (const float*)d_in[14];
    const float* fc1b = (const float*)d_in[15];
    const float* fc2W = (const float*)d_in[16];
    const float* fc2b = (const float*)d_in[17];
    float* out = (float*)d_out;

    const int N = in_sizes[0] / 128;
    const int E = in_sizes[1] / 2;
    const int Et = E + N;
    const int NB = (N + 127) >> 7;           // 128-node buckets

    char* p = (char*)d_ws;
    auto carve = [&](size_t bytes) {
        void* q = p;
        p += (bytes + 255) & ~(size_t)255;
        return q;
    };
    _Float16* h1    = (_Float16*)carve((size_t)N * 256 * 2);
    _Float16* hln1h = (_Float16*)carve((size_t)N * 256 * 2);
    _Float16* h2    = (_Float16*)carve((size_t)N * 64 * 2);
    float* als1 = (float*)carve((size_t)N * 4 * 4);
    float* ald1 = (float*)carve((size_t)N * 4 * 4);
    float* als2 = (float*)carve((size_t)N * 4);
    float* ald2 = (float*)carve((size_t)N * 4);
    int* offs   = (int*)carve((size_t)(N + 1) * 4);
    int* eidx   = (int*)carve((size_t)Et * 4);
    int2* staged  = (int2*)carve((size_t)Et * 8);
    int* gcount  = (int*)carve(512 * 4);
    int* gbase   = (int*)carve(512 * 4);
    int* gcursor = (int*)carve(512 * 4);

    // CSR build (bucketed counting sort; no per-edge global atomics)
    const int nchunks = (Et + 8191) / 8192;
    k_zero<<<(NB + 255) / 256, 256, 0, stream>>>(gcount, NB);
    k_bcount<<<nchunks, 256, 0, stream>>>(ei, gcount, E, N, NB);
    k_bscan<<<1, 512, 0, stream>>>(gcount, gbase, gcursor, offs, NB, N, Et);
    k_bscatter<<<nchunks, 256, 0, stream>>>(ei, gcursor, staged, E, N, NB);
    k_bbuild<<<NB, 256, 0, stream>>>(staged, gcount, gbase, offs, eidx, N);

    // layer 1
    k_gemm1<<<(N + 63) / 64, 256, 0, stream>>>(x, W1, as1, ad1, h1, als1, ald1, N);
    k_agg1<<<(N + 3) / 4, 256, 0, stream>>>(h1, als1, ald1, offs, eidx, b1, g1, be1, hln1h, N);

    // layer 2
    k_gemm2<<<(N + 63) / 64, 256, 0, stream>>>(hln1h, W2, as2, ad2, h2, als2, ald2, N);
    k_agg2<<<(N + 3) / 4, 256, 0, stream>>>(h2, als2, ald2, offs, eidx,
                                            b2, g2, be2, fc1W, fc1b, fc2W, fc2b, out, N);
}